// Round 4
// baseline (665.049 us; speedup 1.0000x reference)
//
#include <hip/hip_runtime.h>

#define BN   64
#define CIN  512
#define COUT 512
#define HW   784
#define NT   128      /* fallback o-tile */
#define MT   112
#define BK   64
#define NKB  (CIN / BK)   /* 8 k-blocks */

typedef __attribute__((ext_vector_type(8))) short short8;
typedef __attribute__((ext_vector_type(4))) float f32x4;

__device__ __forceinline__ unsigned short f2bf(float f) {
    union { float f; unsigned int u; } v; v.f = f;
    unsigned int r = v.u + 0x7fffu + ((v.u >> 16) & 1u);   // RNE
    return (unsigned short)(r >> 16);
}

__device__ __forceinline__ uint2 pack4(float a, float b, float c, float d) {
    uint2 r;
    r.x = (unsigned int)f2bf(a) | ((unsigned int)f2bf(b) << 16);
    r.y = (unsigned int)f2bf(c) | ((unsigned int)f2bf(d) << 16);
    return r;
}

__device__ __forceinline__ void gl_lds16(const float* g, unsigned short* l) {
    __builtin_amdgcn_global_load_lds(
        (const __attribute__((address_space(1))) unsigned int*)g,
        (__attribute__((address_space(3))) unsigned int*)l,
        16, 0, 0);
}

// ---------------- Pass 0: W f32 -> bf16 (tiny, 1.5 MB traffic) ----------------
__global__ __launch_bounds__(256)
void p0_wcvt(const float* __restrict__ W, unsigned short* __restrict__ Wb)
{
    int gi = blockIdx.x * 256 + threadIdx.x;        // 32768 granules of 8
    const float* p = W + (size_t)gi * 8;
    float4 a = *(const float4*)p;
    float4 c = *(const float4*)(p + 4);
    uint2 lo = pack4(a.x, a.y, a.z, a.w);
    uint2 hi = pack4(c.x, c.y, c.z, c.w);
    uint4 v; v.x = lo.x; v.y = lo.y; v.z = hi.x; v.w = hi.y;
    *(uint4*)(Wb + (size_t)gi * 8) = v;
}

// ---------------- Fused v2: glds raw staging + LDS transpose + full-COUT GEMM ----------------
// 512 thr / 8 waves; wave = 64o x 112hw (acc[4][7]). LDS 46 KB -> 3 blocks/CU residency,
// all 448 blocks co-resident. x gather via global_load_lds (h-shift on source addr,
// w-shift applied during in-LDS transpose). Raw buffer sigma-swizzled for conflict-free
// transpose reads (swizzle on glds SOURCE, LDS linear).
__global__ __launch_bounds__(512, 6)
void p_fused(const float* __restrict__ x, const unsigned short* __restrict__ Wb,
             const float* __restrict__ gamma, const float* __restrict__ beta,
             const float* __restrict__ rmean, const float* __restrict__ rvar,
             float* __restrict__ out)
{
    __shared__ float sR[64 * 128];                 // 32768 B raw f32, rows padded to 128
    __shared__ unsigned short sB[MT * BK];         // 14336 B bf16 transposed

    const int t  = threadIdx.x;
    // bijective XCD swizzle (448 = 8 x 56): each XCD owns 56 consecutive logical tiles
    const int id = (blockIdx.x & 7) * 56 + (blockIdx.x >> 3);
    const int mt = id % 7;
    const int b  = id / 7;
    const int hw_base = mt * MT;
    const int lane = t & 63, wv = t >> 6, m16 = lane & 15, q = lane >> 4;
    const float* xb = x + (size_t)b * CIN * HW;
    unsigned short* sR16 = (unsigned short*)sR;

    // transpose mapping: one 4c x 4hw micro-tile per thread (448 active)
    const int cq = t & 15;                      // c-quad within BK
    const int mq = t >> 4;                      // hw-quad 0..27; active when < 28
    const bool act = (mq < 28);

    // ---- staging: 4 glds per thread, granule = i*512 + t ----
    // raw slot p holds logical hw-quad jl = (p&24) | ((p&7) ^ ((c>>2)&7)); jl>=28 -> pad
    auto STAGE = [&](int kk) {
        const int g = kk >> 1;
        #pragma unroll
        for (int i = 0; i < 4; ++i) {
            const int gr_ = i * 512 + t;            // granule 0..2047
            const int c   = gr_ >> 5;               // raw row 0..63
            const int jp  = gr_ & 31;               // physical slot
            const int jl  = (jp & 24) | ((jp & 7) ^ ((c >> 2) & 7));
            const float* crow = xb + (size_t)(kk * BK + c) * HW;
            const float* src;
            if (jl < 28) {
                int hw0 = hw_base + jl * 4;
                if (g == 0) { hw0 += 28; if (hw0 >= HW) hw0 -= HW; }
                else if (g == 1) { hw0 -= 28; if (hw0 < 0) hw0 += HW; }
                src = crow + hw0;                   // g>=2: exact granule (shift in LDS)
            } else {
                src = crow + hw_base;               // pad slot: safe dummy
            }
            const int gbase = i * 512 + (t & ~63);  // wave-uniform granule base
            gl_lds16(src, sR16 + (size_t)gbase * 8);
        }
    };

    // ---- transpose: raw f32 -> shifted bf16, proven xor-granule layout ----
    auto TRANS = [&](int kk) {
        if (!act) return;
        const int g  = kk >> 1;
        const int sg = cq & 7;                      // sigma(c) = (c>>2)&7 = cq&7
        const int p  = (mq & 24) | ((mq & 7) ^ sg);
        const int c0 = cq * 4;
        float4 a0 = *(const float4*)&sR[(c0 + 0) * 128 + p * 4];
        float4 a1 = *(const float4*)&sR[(c0 + 1) * 128 + p * 4];
        float4 a2 = *(const float4*)&sR[(c0 + 2) * 128 + p * 4];
        float4 a3 = *(const float4*)&sR[(c0 + 3) * 128 + p * 4];
        float4 r0 = a0, r1 = a1, r2 = a2, r3 = a3;
        if (g >= 2) {
            const int m7 = mq % 7;
            const int nb = (g == 2) ? ((m7 == 6) ? mq - 6 : mq + 1)
                                    : ((m7 == 0) ? mq + 6 : mq - 1);
            const int np = (nb & 24) | ((nb & 7) ^ sg);
            const int so = (g == 2) ? 0 : 3;
            float e0 = sR[(c0 + 0) * 128 + np * 4 + so];
            float e1 = sR[(c0 + 1) * 128 + np * 4 + so];
            float e2 = sR[(c0 + 2) * 128 + np * 4 + so];
            float e3 = sR[(c0 + 3) * 128 + np * 4 + so];
            if (g == 2) {       // roll -1 along W: out[w] = x[w+1]
                r0 = make_float4(a0.y, a0.z, a0.w, e0);
                r1 = make_float4(a1.y, a1.z, a1.w, e1);
                r2 = make_float4(a2.y, a2.z, a2.w, e2);
                r3 = make_float4(a3.y, a3.z, a3.w, e3);
            } else {            // roll +1 along W: out[w] = x[w-1]
                r0 = make_float4(e0, a0.x, a0.y, a0.z);
                r1 = make_float4(e1, a1.x, a1.y, a1.z);
                r2 = make_float4(e2, a2.x, a2.y, a2.z);
                r3 = make_float4(e3, a3.x, a3.y, a3.z);
            }
        }
        uint2 u0 = pack4(r0.x, r1.x, r2.x, r3.x);
        uint2 u1 = pack4(r0.y, r1.y, r2.y, r3.y);
        uint2 u2 = pack4(r0.z, r1.z, r2.z, r3.z);
        uint2 u3 = pack4(r0.w, r1.w, r2.w, r3.w);
        const int m0 = mq * 4;
        const int gr = cq >> 1, hf4 = (cq & 1) * 4;
        *(uint2*)(&sB[(m0 + 0) * BK + ((gr ^ ((m0 + 0) & 7)) * 8) + hf4]) = u0;
        *(uint2*)(&sB[(m0 + 1) * BK + ((gr ^ ((m0 + 1) & 7)) * 8) + hf4]) = u1;
        *(uint2*)(&sB[(m0 + 2) * BK + ((gr ^ ((m0 + 2) & 7)) * 8) + hf4]) = u2;
        *(uint2*)(&sB[(m0 + 3) * BK + ((gr ^ ((m0 + 3) & 7)) * 8) + hf4]) = u3;
    };

    // W row pointers: 4 o-frags of 16 per wave, k-offset q*8
    const unsigned short* wr0 = Wb + (size_t)(wv * 64 + m16) * CIN + q * 8;
    const unsigned short* wr1 = wr0 + 16 * CIN;
    const unsigned short* wr2 = wr0 + 32 * CIN;
    const unsigned short* wr3 = wr0 + 48 * CIN;

    short8 wA[8], wB[8];
#define LOADW(DST, KK)                                  \
    {   const int ko = (KK) * 64;                       \
        DST[0] = *(const short8*)(wr0 + ko);            \
        DST[1] = *(const short8*)(wr1 + ko);            \
        DST[2] = *(const short8*)(wr2 + ko);            \
        DST[3] = *(const short8*)(wr3 + ko);            \
        DST[4] = *(const short8*)(wr0 + ko + 32);       \
        DST[5] = *(const short8*)(wr1 + ko + 32);       \
        DST[6] = *(const short8*)(wr2 + ko + 32);       \
        DST[7] = *(const short8*)(wr3 + ko + 32);       \
    }

    f32x4 acc[4][7];
    #pragma unroll
    for (int i = 0; i < 4; ++i)
        #pragma unroll
        for (int j = 0; j < 7; ++j)
            acc[i][j] = (f32x4){0.f, 0.f, 0.f, 0.f};

#define MFMA16(A, B, C) __builtin_amdgcn_mfma_f32_16x16x32_bf16((A), (B), (C), 0, 0, 0)
#define COMPUTE(WF)                                                              \
    {                                                                            \
        _Pragma("unroll")                                                        \
        for (int bm = 0; bm < 7; ++bm) {                                         \
            int m   = bm * 16 + m16;                                             \
            int sl0 = q ^ (m & 7);                                               \
            int sl1 = (4 + q) ^ (m & 7);                                         \
            short8 bf0 = *(const short8*)(&sB[m * BK + sl0 * 8]);                \
            short8 bf1 = *(const short8*)(&sB[m * BK + sl1 * 8]);                \
            acc[0][bm] = MFMA16(WF[0], bf0, acc[0][bm]);                         \
            acc[1][bm] = MFMA16(WF[1], bf0, acc[1][bm]);                         \
            acc[2][bm] = MFMA16(WF[2], bf0, acc[2][bm]);                         \
            acc[3][bm] = MFMA16(WF[3], bf0, acc[3][bm]);                         \
            acc[0][bm] = MFMA16(WF[4], bf1, acc[0][bm]);                         \
            acc[1][bm] = MFMA16(WF[5], bf1, acc[1][bm]);                         \
            acc[2][bm] = MFMA16(WF[6], bf1, acc[2][bm]);                         \
            acc[3][bm] = MFMA16(WF[7], bf1, acc[3][bm]);                         \
        }                                                                        \
    }

    // prologue: stage k0 raw + W0; barrier drains own-wave glds (implicit vmcnt(0))
    STAGE(0);
    LOADW(wA, 0);
    __syncthreads();

    // phase kk: TRANS(kk) | bar | STAGE(kk+1) + LOADW(next) + COMPUTE(kk) | bar
#define PHASE_E(KK)   /* even: compute wA, prefetch wB */                        \
    TRANS(KK);                                                                   \
    __syncthreads();                                                             \
    if ((KK) < 7) { STAGE((KK) + 1); LOADW(wB, (KK) + 1); }                      \
    COMPUTE(wA);                                                                 \
    if ((KK) < 7) __syncthreads();
#define PHASE_O(KK)   /* odd: compute wB, prefetch wA */                         \
    TRANS(KK);                                                                   \
    __syncthreads();                                                             \
    if ((KK) < 7) { STAGE((KK) + 1); LOADW(wA, (KK) + 1); }                      \
    COMPUTE(wB);                                                                 \
    if ((KK) < 7) __syncthreads();

    PHASE_E(0)
    PHASE_O(1)
    PHASE_E(2)
    PHASE_O(3)
    PHASE_E(4)
    PHASE_O(5)
    PHASE_E(6)
    PHASE_O(7)
#undef PHASE_E
#undef PHASE_O
#undef COMPUTE
#undef MFMA16
#undef LOADW

    // epilogue: BN fold + ReLU + nontemporal store
    float scl[4][4], shf[4][4];
    #pragma unroll
    for (int bo = 0; bo < 4; ++bo)
        #pragma unroll
        for (int r = 0; r < 4; ++r) {
            int o = wv * 64 + bo * 16 + q * 4 + r;
            float sc = gamma[o] * rsqrtf(rvar[o] + 1e-5f);
            scl[bo][r] = sc;
            shf[bo][r] = beta[o] - rmean[o] * sc;
        }
    float* outb = out + (size_t)b * COUT * HW;
    #pragma unroll
    for (int bo = 0; bo < 4; ++bo) {
        #pragma unroll
        for (int r = 0; r < 4; ++r) {
            int o = wv * 64 + bo * 16 + q * 4 + r;
            float* orow = outb + (size_t)o * HW + hw_base + m16;
            #pragma unroll
            for (int bm = 0; bm < 7; ++bm) {
                float y = acc[bo][bm][r] * scl[bo][r] + shf[bo][r];
                y = fmaxf(y, 0.f);
                __builtin_nontemporal_store(y, orow + bm * 16);
            }
        }
    }
}

// ---------------- Fallback (ws too small): round-1 single-pass ----------------
#define SW_STRIDE 72
#define SX_STRIDE 64
__global__ __launch_bounds__(256, 2)
void shiftconv_fallback(const float* __restrict__ x, const float* __restrict__ Wf,
                        const float* __restrict__ gamma, const float* __restrict__ beta,
                        const float* __restrict__ rmean, const float* __restrict__ rvar,
                        float* __restrict__ out)
{
    __shared__ unsigned short sW[NT * SW_STRIDE];
    __shared__ unsigned short sX[MT * SX_STRIDE];
    const int t = threadIdx.x;
    const int ot = blockIdx.x, mt = blockIdx.y, b = blockIdx.z;
    const int o_base = ot * NT, hw_base = mt * MT;
    const float* xb = x + (size_t)b * CIN * HW;
    const int lane = t & 63, wv = t >> 6, m16 = lane & 15, q = lane >> 4;
    f32x4 acc[2][7];
    #pragma unroll
    for (int i = 0; i < 2; ++i)
        #pragma unroll
        for (int j = 0; j < 7; ++j) acc[i][j] = (f32x4){0.f, 0.f, 0.f, 0.f};
    #pragma unroll
    for (int kk = 0; kk < CIN / BK; ++kk) {
        const int k0 = kk * BK;
        const int g = k0 >> 7;
        #pragma unroll
        for (int e0 = 0; e0 < 2; ++e0) {
            int e = t + e0 * 256;
            if (e < (BK / 4) * (MT / 4)) {
                int cq = e / 28, mq = e - cq * 28;
                int hw = hw_base + mq * 4;
                const float* src = xb + (size_t)(k0 + cq * 4) * HW;
                float4 v0, v1, v2, v3;
                if (g < 2) {
                    int shw = hw + (g == 0 ? 28 : HW - 28);
                    if (shw >= HW) shw -= HW;
                    v0 = *(const float4*)(src + 0 * HW + shw);
                    v1 = *(const float4*)(src + 1 * HW + shw);
                    v2 = *(const float4*)(src + 2 * HW + shw);
                    v3 = *(const float4*)(src + 3 * HW + shw);
                } else {
                    int h = hw / 28, w0 = hw - h * 28, base = h * 28;
                    #pragma unroll
                    for (int j = 0; j < 4; ++j) {
                        const float* row = src + j * HW + base;
                        float4 a = *(const float4*)(row + w0);
                        float4 r;
                        if (g == 2) {
                            float ex = row[(w0 + 4 < 28) ? (w0 + 4) : 0];
                            r.x = a.y; r.y = a.z; r.z = a.w; r.w = ex;
                        } else {
                            float ex = row[(w0 == 0) ? 27 : (w0 - 1)];
                            r.x = ex; r.y = a.x; r.z = a.y; r.w = a.z;
                        }
                        if (j == 0) v0 = r; else if (j == 1) v1 = r;
                        else if (j == 2) v2 = r; else v3 = r;
                    }
                }
                int m0 = mq * 4;
                { int p = (cq + 5 * (m0 + 0)) & 15;
                  *(uint2*)(&sX[(m0 + 0) * SX_STRIDE + p * 4]) = pack4(v0.x, v1.x, v2.x, v3.x); }
                { int p = (cq + 5 * (m0 + 1)) & 15;
                  *(uint2*)(&sX[(m0 + 1) * SX_STRIDE + p * 4]) = pack4(v0.y, v1.y, v2.y, v3.y); }
                { int p = (cq + 5 * (m0 + 2)) & 15;
                  *(uint2*)(&sX[(m0 + 2) * SX_STRIDE + p * 4]) = pack4(v0.z, v1.z, v2.z, v3.z); }
                { int p = (cq + 5 * (m0 + 3)) & 15;
                  *(uint2*)(&sX[(m0 + 3) * SX_STRIDE + p * 4]) = pack4(v0.w, v1.w, v2.w, v3.w); }
            }
        }
        #pragma unroll
        for (int i = 0; i < 4; ++i) {
            int e = t + i * 256;
            int ol = e >> 3, kg = (e & 7) * 8;
            const float* wr = Wf + (size_t)(o_base + ol) * CIN + k0 + kg;
            float4 a = *(const float4*)(wr);
            float4 c = *(const float4*)(wr + 4);
            uint2 lo = pack4(a.x, a.y, a.z, a.w);
            uint2 hi = pack4(c.x, c.y, c.z, c.w);
            uint4 v; v.x = lo.x; v.y = lo.y; v.z = hi.x; v.w = hi.y;
            *(uint4*)(&sW[ol * SW_STRIDE + kg]) = v;
        }
        __syncthreads();
        #pragma unroll
        for (int ks = 0; ks < BK; ks += 32) {
            short8 afrag[2];
            #pragma unroll
            for (int bo = 0; bo < 2; ++bo) {
                int row = wv * 32 + bo * 16 + m16;
                afrag[bo] = *(const short8*)(&sW[row * SW_STRIDE + ks + q * 8]);
            }
            #pragma unroll
            for (int bm = 0; bm < 7; ++bm) {
                int m = bm * 16 + m16;
                int g0 = (ks >> 2) + 2 * q;
                int p0 = (g0 + 5 * m) & 15;
                int p1 = (g0 + 1 + 5 * m) & 15;
                uint2 lo = *(const uint2*)(&sX[m * SX_STRIDE + p0 * 4]);
                uint2 hi = *(const uint2*)(&sX[m * SX_STRIDE + p1 * 4]);
                union { uint2 u2[2]; short8 s; } fb;
                fb.u2[0] = lo; fb.u2[1] = hi;
                acc[0][bm] = __builtin_amdgcn_mfma_f32_16x16x32_bf16(afrag[0], fb.s, acc[0][bm], 0, 0, 0);
                acc[1][bm] = __builtin_amdgcn_mfma_f32_16x16x32_bf16(afrag[1], fb.s, acc[1][bm], 0, 0, 0);
            }
        }
        __syncthreads();
    }
    float scl[2][4], shf[2][4];
    #pragma unroll
    for (int bo = 0; bo < 2; ++bo)
        #pragma unroll
        for (int r = 0; r < 4; ++r) {
            int o = o_base + wv * 32 + bo * 16 + q * 4 + r;
            float sc = gamma[o] * rsqrtf(rvar[o] + 1e-5f);
            scl[bo][r] = sc;
            shf[bo][r] = beta[o] - rmean[o] * sc;
        }
    float* outb = out + (size_t)b * COUT * HW;
    #pragma unroll
    for (int bo = 0; bo < 2; ++bo)
        #pragma unroll
        for (int r = 0; r < 4; ++r) {
            int o = o_base + wv * 32 + bo * 16 + q * 4 + r;
            float* orow = outb + (size_t)o * HW + hw_base + m16;
            #pragma unroll
            for (int bm = 0; bm < 7; ++bm) {
                float y = acc[bo][bm][r] * scl[bo][r] + shf[bo][r];
                y = fmaxf(y, 0.f);
                __builtin_nontemporal_store(y, orow + bm * 16);
            }
        }
}

extern "C" void kernel_launch(void* const* d_in, const int* in_sizes, int n_in,
                              void* d_out, int out_size, void* d_ws, size_t ws_size,
                              hipStream_t stream)
{
    const float* x     = (const float*)d_in[0];
    const float* W     = (const float*)d_in[1];
    const float* gamma = (const float*)d_in[2];
    const float* beta  = (const float*)d_in[3];
    const float* rmean = (const float*)d_in[4];
    const float* rvar  = (const float*)d_in[5];
    float* out = (float*)d_out;

    const size_t wb_bytes = (size_t)COUT * CIN * 2;                 // 512 KB
    if (ws_size >= wb_bytes) {
        unsigned short* Wb = (unsigned short*)d_ws;
        p0_wcvt<<<dim3(128), dim3(256), 0, stream>>>(W, Wb);
        p_fused<<<dim3(448), dim3(512), 0, stream>>>(x, Wb, gamma, beta, rmean, rvar, out);
    } else {
        dim3 grid(COUT / NT, HW / MT, BN);
        shiftconv_fallback<<<grid, 256, 0, stream>>>(x, W, gamma, beta, rmean, rvar, out);
    }
}

// Round 5
// 258.700 us; speedup vs baseline: 2.5707x; 2.5707x over previous
//
#include <hip/hip_runtime.h>

#define BN   64
#define CIN  512
#define COUT 512
#define HW   784
#define NT   128      /* fallback o-tile */
#define MT   112
#define BK   64
#define NKB  (CIN / BK)   /* 8 k-blocks */
#define TROW 68           /* p1 LDS: 17 granules x 4 ushorts */

typedef __attribute__((ext_vector_type(8))) short short8;
typedef __attribute__((ext_vector_type(4))) float f32x4;

__device__ __forceinline__ unsigned short f2bf(float f) {
    union { float f; unsigned int u; } v; v.f = f;
    unsigned int r = v.u + 0x7fffu + ((v.u >> 16) & 1u);   // RNE
    return (unsigned short)(r >> 16);
}

__device__ __forceinline__ uint2 pack4(float a, float b, float c, float d) {
    uint2 r;
    r.x = (unsigned int)f2bf(a) | ((unsigned int)f2bf(b) << 16);
    r.y = (unsigned int)f2bf(c) | ((unsigned int)f2bf(d) << 16);
    return r;
}

// ---------------- Pass 0: W f32 -> bf16, A-FRAGMENT-major layout ----------------
// Wb[ofrag=o>>4][kgran=c>>3 (128 ushorts each)][m16=o&15][8c]
__global__ __launch_bounds__(256)
void p0_wcvt(const float* __restrict__ W, unsigned short* __restrict__ Wb)
{
    int gi = blockIdx.x * 256 + threadIdx.x;        // 32768 granules of 8
    const float* p = W + (size_t)gi * 8;
    float4 a = *(const float4*)p;
    float4 c = *(const float4*)(p + 4);
    uint2 lo = pack4(a.x, a.y, a.z, a.w);
    uint2 hi = pack4(c.x, c.y, c.z, c.w);
    uint4 v; v.x = lo.x; v.y = lo.y; v.z = hi.x; v.w = hi.y;
    int o = gi >> 6, j = gi & 63;
    *(uint4*)(Wb + (size_t)(o >> 4) * 8192 + j * 128 + (o & 15) * 8) = v;
}

// ---------------- Pass 1: shift + cvt + LDS transpose (round-0 proven) ----------------
// Xt slab (b,kk,mt) = 7168 ushorts in B-FRAGMENT order:
//   offset = bm*1024 + ks*512 + m16*32 + q*8   (m = bm*16+m16, c-granule j = ks*4+q)
__global__ __launch_bounds__(448)
void p1_shift_cvt(const float* __restrict__ x, unsigned short* __restrict__ Xt)
{
    __shared__ unsigned short sT[MT * TROW];   // 15232 B
    const int t = threadIdx.x;
    const int kk = blockIdx.x;            // c-block of 64
    const int mt = blockIdx.y;            // hw-tile of 112
    const int b  = blockIdx.z;
    const int g  = kk >> 1;               // shift group (block-uniform)
    const int c0 = kk * BK;
    const int hw_base = mt * MT;
    const float* xb = x + (size_t)b * CIN * HW;

    // Phase A: one 4c x 4hw micro-tile per lane (448 items, 448 lanes)
    {
        const int cq = t / 28;            // 0..15
        const int mq = t - cq * 28;       // 0..27
        const int hw = hw_base + mq * 4;
        const float* src = xb + (size_t)(c0 + cq * 4) * HW;
        float4 v0, v1, v2, v3;
        if (g < 2) {
            int shw = hw + (g == 0 ? 28 : HW - 28);
            if (shw >= HW) shw -= HW;
            v0 = *(const float4*)(src + 0 * HW + shw);
            v1 = *(const float4*)(src + 1 * HW + shw);
            v2 = *(const float4*)(src + 2 * HW + shw);
            v3 = *(const float4*)(src + 3 * HW + shw);
        } else {
            int h  = hw / 28;
            int w0 = hw - h * 28;
            int base = h * 28;
            #pragma unroll
            for (int j = 0; j < 4; ++j) {
                const float* row = src + j * HW + base;
                float4 a = *(const float4*)(row + w0);
                float4 r;
                if (g == 2) {
                    float ex = row[(w0 + 4 < 28) ? (w0 + 4) : 0];
                    r.x = a.y; r.y = a.z; r.z = a.w; r.w = ex;
                } else {
                    float ex = row[(w0 == 0) ? 27 : (w0 - 1)];
                    r.x = ex; r.y = a.x; r.z = a.y; r.w = a.z;
                }
                if (j == 0) v0 = r; else if (j == 1) v1 = r;
                else if (j == 2) v2 = r; else v3 = r;
            }
        }
        const int m0 = mq * 4;
        const int p  = (cq + mq) % 17;    // granule swizzle: bank step 10 mod 32
        *(uint2*)(&sT[(m0 + 0) * TROW + p * 4]) = pack4(v0.x, v1.x, v2.x, v3.x);
        *(uint2*)(&sT[(m0 + 1) * TROW + p * 4]) = pack4(v0.y, v1.y, v2.y, v3.y);
        *(uint2*)(&sT[(m0 + 2) * TROW + p * 4]) = pack4(v0.z, v1.z, v2.z, v3.z);
        *(uint2*)(&sT[(m0 + 3) * TROW + p * 4]) = pack4(v0.w, v1.w, v2.w, v3.w);
    }
    __syncthreads();

    // Phase B: 16B stores in fragment order (wave covers two full 512B regions)
    unsigned short* Xb = Xt + (size_t)((b * NKB + kk) * 7 + mt) * 7168;
    #pragma unroll
    for (int e0 = 0; e0 < 2; ++e0) {
        int ch = t + e0 * 448;            // 896 chunks
        int m = ch >> 3, j = ch & 7;
        int q4 = m >> 2;
        int pa = (2 * j + q4) % 17;
        int pb = (2 * j + 1 + q4) % 17;
        uint2 a = *(const uint2*)(&sT[m * TROW + pa * 4]);
        uint2 c = *(const uint2*)(&sT[m * TROW + pb * 4]);
        uint4 v; v.x = a.x; v.y = a.y; v.z = c.x; v.w = c.y;
        *(uint4*)(Xb + (m >> 4) * 1024 + (j >> 2) * 512 + (m & 15) * 32 + (j & 3) * 8) = v;
    }
}

// ---------------- Pass 2: barrier-free streaming GEMM (no LDS) ----------------
// 256 thr / 4 waves, o-tile 256 (wave = 64o x 112hw, acc[4][7] in AGPR).
// B-frags direct from fragment-major Xt (1 KiB coalesced per wave-load, L2/L3-hot);
// A-frags from fragment-major Wb. Fully unrolled 448-MFMA body, zero syncs.
__global__ __launch_bounds__(256, 2)
void p2_gemm(const unsigned short* __restrict__ Wb, const unsigned short* __restrict__ Xt,
             const float* __restrict__ gamma, const float* __restrict__ beta,
             const float* __restrict__ rmean, const float* __restrict__ rvar,
             float* __restrict__ out)
{
    const int t  = threadIdx.x;
    // XCD pairing: the 2 o-halves of one (b,mt) at ids {base, base+8} -> same XCD
    const int id   = blockIdx.x;                 // 0..895
    const int ot   = (id >> 3) & 1;
    const int pair = ((id >> 4) << 3) | (id & 7);   // 0..447
    const int mt   = pair % 7;
    const int b    = pair / 7;
    const int o_base  = ot * 256;
    const int hw_base = mt * MT;
    const int lane = t & 63, wv = t >> 6, m16 = lane & 15, q = lane >> 4;

    const unsigned short* Xs = Xt + (size_t)((b * NKB) * 7 + mt) * 7168 + m16 * 32 + q * 8;
    const unsigned short* Wf = Wb + (size_t)((o_base + wv * 64) >> 4) * 8192 + q * 128 + m16 * 8;

    f32x4 acc[4][7];
    #pragma unroll
    for (int i = 0; i < 4; ++i)
        #pragma unroll
        for (int j = 0; j < 7; ++j)
            acc[i][j] = (f32x4){0.f, 0.f, 0.f, 0.f};

#define MFMA16(A, B, C) __builtin_amdgcn_mfma_f32_16x16x32_bf16((A), (B), (C), 0, 0, 0)
    #pragma unroll
    for (int kk = 0; kk < NKB; ++kk) {
        const unsigned short* xk = Xs + (size_t)kk * (7 * 7168);
        const unsigned short* wk = Wf + kk * 1024;
        short8 w00 = *(const short8*)(wk + 0 * 8192);
        short8 w01 = *(const short8*)(wk + 1 * 8192);
        short8 w02 = *(const short8*)(wk + 2 * 8192);
        short8 w03 = *(const short8*)(wk + 3 * 8192);
        short8 w10 = *(const short8*)(wk + 0 * 8192 + 512);
        short8 w11 = *(const short8*)(wk + 1 * 8192 + 512);
        short8 w12 = *(const short8*)(wk + 2 * 8192 + 512);
        short8 w13 = *(const short8*)(wk + 3 * 8192 + 512);
        #pragma unroll
        for (int bm = 0; bm < 7; ++bm) {
            short8 b0 = *(const short8*)(xk + bm * 1024);
            short8 b1 = *(const short8*)(xk + bm * 1024 + 512);
            acc[0][bm] = MFMA16(w00, b0, acc[0][bm]);
            acc[1][bm] = MFMA16(w01, b0, acc[1][bm]);
            acc[2][bm] = MFMA16(w02, b0, acc[2][bm]);
            acc[3][bm] = MFMA16(w03, b0, acc[3][bm]);
            acc[0][bm] = MFMA16(w10, b1, acc[0][bm]);
            acc[1][bm] = MFMA16(w11, b1, acc[1][bm]);
            acc[2][bm] = MFMA16(w12, b1, acc[2][bm]);
            acc[3][bm] = MFMA16(w13, b1, acc[3][bm]);
        }
    }
#undef MFMA16

    // epilogue: BN fold + ReLU + nontemporal store
    float scl[4][4], shf[4][4];
    #pragma unroll
    for (int bo = 0; bo < 4; ++bo)
        #pragma unroll
        for (int r = 0; r < 4; ++r) {
            int o = o_base + wv * 64 + bo * 16 + q * 4 + r;
            float sc = gamma[o] * rsqrtf(rvar[o] + 1e-5f);
            scl[bo][r] = sc;
            shf[bo][r] = beta[o] - rmean[o] * sc;
        }
    float* outb = out + (size_t)b * COUT * HW;
    #pragma unroll
    for (int bo = 0; bo < 4; ++bo) {
        #pragma unroll
        for (int r = 0; r < 4; ++r) {
            int o = o_base + wv * 64 + bo * 16 + q * 4 + r;
            float* orow = outb + (size_t)o * HW + hw_base + m16;
            #pragma unroll
            for (int bm = 0; bm < 7; ++bm) {
                float y = acc[bo][bm][r] * scl[bo][r] + shf[bo][r];
                y = fmaxf(y, 0.f);
                __builtin_nontemporal_store(y, orow + bm * 16);
            }
        }
    }
}

// ---------------- Fallback (ws too small): round-1 single-pass ----------------
#define SW_STRIDE 72
#define SX_STRIDE 64
__global__ __launch_bounds__(256, 2)
void shiftconv_fallback(const float* __restrict__ x, const float* __restrict__ Wf,
                        const float* __restrict__ gamma, const float* __restrict__ beta,
                        const float* __restrict__ rmean, const float* __restrict__ rvar,
                        float* __restrict__ out)
{
    __shared__ unsigned short sW[NT * SW_STRIDE];
    __shared__ unsigned short sX[MT * SX_STRIDE];
    const int t = threadIdx.x;
    const int ot = blockIdx.x, mt = blockIdx.y, b = blockIdx.z;
    const int o_base = ot * NT, hw_base = mt * MT;
    const float* xb = x + (size_t)b * CIN * HW;
    const int lane = t & 63, wv = t >> 6, m16 = lane & 15, q = lane >> 4;
    f32x4 acc[2][7];
    #pragma unroll
    for (int i = 0; i < 2; ++i)
        #pragma unroll
        for (int j = 0; j < 7; ++j) acc[i][j] = (f32x4){0.f, 0.f, 0.f, 0.f};
    #pragma unroll
    for (int kk = 0; kk < CIN / BK; ++kk) {
        const int k0 = kk * BK;
        const int g = k0 >> 7;
        #pragma unroll
        for (int e0 = 0; e0 < 2; ++e0) {
            int e = t + e0 * 256;
            if (e < (BK / 4) * (MT / 4)) {
                int cq = e / 28, mq = e - cq * 28;
                int hw = hw_base + mq * 4;
                const float* src = xb + (size_t)(k0 + cq * 4) * HW;
                float4 v0, v1, v2, v3;
                if (g < 2) {
                    int shw = hw + (g == 0 ? 28 : HW - 28);
                    if (shw >= HW) shw -= HW;
                    v0 = *(const float4*)(src + 0 * HW + shw);
                    v1 = *(const float4*)(src + 1 * HW + shw);
                    v2 = *(const float4*)(src + 2 * HW + shw);
                    v3 = *(const float4*)(src + 3 * HW + shw);
                } else {
                    int h = hw / 28, w0 = hw - h * 28, base = h * 28;
                    #pragma unroll
                    for (int j = 0; j < 4; ++j) {
                        const float* row = src + j * HW + base;
                        float4 a = *(const float4*)(row + w0);
                        float4 r;
                        if (g == 2) {
                            float ex = row[(w0 + 4 < 28) ? (w0 + 4) : 0];
                            r.x = a.y; r.y = a.z; r.z = a.w; r.w = ex;
                        } else {
                            float ex = row[(w0 == 0) ? 27 : (w0 - 1)];
                            r.x = ex; r.y = a.x; r.z = a.y; r.w = a.z;
                        }
                        if (j == 0) v0 = r; else if (j == 1) v1 = r;
                        else if (j == 2) v2 = r; else v3 = r;
                    }
                }
                int m0 = mq * 4;
                { int p = (cq + 5 * (m0 + 0)) & 15;
                  *(uint2*)(&sX[(m0 + 0) * SX_STRIDE + p * 4]) = pack4(v0.x, v1.x, v2.x, v3.x); }
                { int p = (cq + 5 * (m0 + 1)) & 15;
                  *(uint2*)(&sX[(m0 + 1) * SX_STRIDE + p * 4]) = pack4(v0.y, v1.y, v2.y, v3.y); }
                { int p = (cq + 5 * (m0 + 2)) & 15;
                  *(uint2*)(&sX[(m0 + 2) * SX_STRIDE + p * 4]) = pack4(v0.z, v1.z, v2.z, v3.z); }
                { int p = (cq + 5 * (m0 + 3)) & 15;
                  *(uint2*)(&sX[(m0 + 3) * SX_STRIDE + p * 4]) = pack4(v0.w, v1.w, v2.w, v3.w); }
            }
        }
        #pragma unroll
        for (int i = 0; i < 4; ++i) {
            int e = t + i * 256;
            int ol = e >> 3, kg = (e & 7) * 8;
            const float* wr = Wf + (size_t)(o_base + ol) * CIN + k0 + kg;
            float4 a = *(const float4*)(wr);
            float4 c = *(const float4*)(wr + 4);
            uint2 lo = pack4(a.x, a.y, a.z, a.w);
            uint2 hi = pack4(c.x, c.y, c.z, c.w);
            uint4 v; v.x = lo.x; v.y = lo.y; v.z = hi.x; v.w = hi.y;
            *(uint4*)(&sW[ol * SW_STRIDE + kg]) = v;
        }
        __syncthreads();
        #pragma unroll
        for (int ks = 0; ks < BK; ks += 32) {
            short8 afrag[2];
            #pragma unroll
            for (int bo = 0; bo < 2; ++bo) {
                int row = wv * 32 + bo * 16 + m16;
                afrag[bo] = *(const short8*)(&sW[row * SW_STRIDE + ks + q * 8]);
            }
            #pragma unroll
            for (int bm = 0; bm < 7; ++bm) {
                int m = bm * 16 + m16;
                int g0 = (ks >> 2) + 2 * q;
                int p0 = (g0 + 5 * m) & 15;
                int p1 = (g0 + 1 + 5 * m) & 15;
                uint2 lo = *(const uint2*)(&sX[m * SX_STRIDE + p0 * 4]);
                uint2 hi = *(const uint2*)(&sX[m * SX_STRIDE + p1 * 4]);
                union { uint2 u2[2]; short8 s; } fb;
                fb.u2[0] = lo; fb.u2[1] = hi;
                acc[0][bm] = __builtin_amdgcn_mfma_f32_16x16x32_bf16(afrag[0], fb.s, acc[0][bm], 0, 0, 0);
                acc[1][bm] = __builtin_amdgcn_mfma_f32_16x16x32_bf16(afrag[1], fb.s, acc[1][bm], 0, 0, 0);
            }
        }
        __syncthreads();
    }
    float scl[2][4], shf[2][4];
    #pragma unroll
    for (int bo = 0; bo < 2; ++bo)
        #pragma unroll
        for (int r = 0; r < 4; ++r) {
            int o = o_base + wv * 32 + bo * 16 + q * 4 + r;
            float sc = gamma[o] * rsqrtf(rvar[o] + 1e-5f);
            scl[bo][r] = sc;
            shf[bo][r] = beta[o] - rmean[o] * sc;
        }
    float* outb = out + (size_t)b * COUT * HW;
    #pragma unroll
    for (int bo = 0; bo < 2; ++bo)
        #pragma unroll
        for (int r = 0; r < 4; ++r) {
            int o = o_base + wv * 32 + bo * 16 + q * 4 + r;
            float* orow = outb + (size_t)o * HW + hw_base + m16;
            #pragma unroll
            for (int bm = 0; bm < 7; ++bm) {
                float y = acc[bo][bm][r] * scl[bo][r] + shf[bo][r];
                y = fmaxf(y, 0.f);
                __builtin_nontemporal_store(y, orow + bm * 16);
            }
        }
}

extern "C" void kernel_launch(void* const* d_in, const int* in_sizes, int n_in,
                              void* d_out, int out_size, void* d_ws, size_t ws_size,
                              hipStream_t stream)
{
    const float* x     = (const float*)d_in[0];
    const float* W     = (const float*)d_in[1];
    const float* gamma = (const float*)d_in[2];
    const float* beta  = (const float*)d_in[3];
    const float* rmean = (const float*)d_in[4];
    const float* rvar  = (const float*)d_in[5];
    float* out = (float*)d_out;

    const size_t wb_bytes = (size_t)COUT * CIN * 2;                 // 512 KB
    const size_t xt_bytes = (size_t)BN * CIN * HW * 2;              // ~51.4 MB
    if (ws_size >= wb_bytes + xt_bytes) {
        unsigned short* Wb = (unsigned short*)d_ws;
        unsigned short* Xt = (unsigned short*)((char*)d_ws + wb_bytes);
        p0_wcvt<<<dim3(128), dim3(256), 0, stream>>>(W, Wb);
        p1_shift_cvt<<<dim3(8, 7, BN), dim3(448), 0, stream>>>(x, Xt);
        p2_gemm<<<dim3(896), dim3(256), 0, stream>>>(Wb, Xt, gamma, beta, rmean, rvar, out);
    } else {
        dim3 grid(COUT / NT, HW / MT, BN);
        shiftconv_fallback<<<grid, 256, 0, stream>>>(x, W, gamma, beta, rmean, rvar, out);
    }
}

// Round 6
// 232.194 us; speedup vs baseline: 2.8642x; 1.1142x over previous
//
#include <hip/hip_runtime.h>

#define BN   64
#define CIN  512
#define COUT 512
#define HW   784
#define NT   128      /* fallback o-tile */
#define MT   112
#define BK   64
#define NKB  (CIN / BK)
#define TROW 68   /* 17 granules x 8B = 136 B rows */

typedef __attribute__((ext_vector_type(8))) short short8;
typedef __attribute__((ext_vector_type(4))) float f32x4;

__device__ __forceinline__ unsigned short f2bf(float f) {
    union { float f; unsigned int u; } v; v.f = f;
    unsigned int r = v.u + 0x7fffu + ((v.u >> 16) & 1u);   // RNE
    return (unsigned short)(r >> 16);
}

__device__ __forceinline__ uint2 pack4(float a, float b, float c, float d) {
    uint2 r;
    r.x = (unsigned int)f2bf(a) | ((unsigned int)f2bf(b) << 16);
    r.y = (unsigned int)f2bf(c) | ((unsigned int)f2bf(d) << 16);
    return r;
}

__device__ __forceinline__ void gl_lds16(const unsigned short* g, unsigned short* l) {
    __builtin_amdgcn_global_load_lds(
        (const __attribute__((address_space(1))) unsigned int*)g,
        (__attribute__((address_space(3))) unsigned int*)l,
        16, 0, 0);
}

// ---------------- Pass 1: shift + cvt + LDS transpose (mod-17 swizzle) ----------------
// grid (8, 7, 65), 448 threads; z==64 blocks convert W -> bf16.
__global__ __launch_bounds__(448)
void p1_shift_cvt(const float* __restrict__ x, const float* __restrict__ W,
                  unsigned short* __restrict__ Wb, unsigned short* __restrict__ Xt)
{
    __shared__ unsigned short sT[MT * TROW];   // 15232 B
    const int t = threadIdx.x;
    if (blockIdx.z == BN) {
        int wlin = blockIdx.x * 7 + blockIdx.y;           // 0..55
        for (int gi = wlin * 448 + t; gi < (COUT * CIN) / 8; gi += 56 * 448) {
            const float* p = W + (size_t)gi * 8;
            float4 a = *(const float4*)p;
            float4 c = *(const float4*)(p + 4);
            uint2 lo = pack4(a.x, a.y, a.z, a.w);
            uint2 hi = pack4(c.x, c.y, c.z, c.w);
            uint4 v; v.x = lo.x; v.y = lo.y; v.z = hi.x; v.w = hi.y;
            *(uint4*)(Wb + (size_t)gi * 8) = v;
        }
        return;
    }
    const int kk = blockIdx.x;            // c-block of 64
    const int mt = blockIdx.y;            // hw-tile of 112
    const int b  = blockIdx.z;
    const int g  = kk >> 1;               // shift group (block-uniform)
    const int c0 = kk * BK;
    const int hw_base = mt * MT;
    const float* xb = x + (size_t)b * CIN * HW;

    // Phase A: one 4c x 4hw micro-tile per lane (448 items, 448 lanes)
    {
        const int cq = t / 28;            // 0..15
        const int mq = t - cq * 28;       // 0..27
        const int hw = hw_base + mq * 4;
        const float* src = xb + (size_t)(c0 + cq * 4) * HW;
        float4 v0, v1, v2, v3;
        if (g < 2) {
            int shw = hw + (g == 0 ? 28 : HW - 28);
            if (shw >= HW) shw -= HW;
            v0 = *(const float4*)(src + 0 * HW + shw);
            v1 = *(const float4*)(src + 1 * HW + shw);
            v2 = *(const float4*)(src + 2 * HW + shw);
            v3 = *(const float4*)(src + 3 * HW + shw);
        } else {
            int h  = hw / 28;
            int w0 = hw - h * 28;
            int base = h * 28;
            #pragma unroll
            for (int j = 0; j < 4; ++j) {
                const float* row = src + j * HW + base;
                float4 a = *(const float4*)(row + w0);
                float4 r;
                if (g == 2) {
                    float ex = row[(w0 + 4 < 28) ? (w0 + 4) : 0];
                    r.x = a.y; r.y = a.z; r.z = a.w; r.w = ex;
                } else {
                    float ex = row[(w0 == 0) ? 27 : (w0 - 1)];
                    r.x = ex; r.y = a.x; r.z = a.y; r.w = a.z;
                }
                if (j == 0) v0 = r; else if (j == 1) v1 = r;
                else if (j == 2) v2 = r; else v3 = r;
            }
        }
        const int m0 = mq * 4;
        const int p  = (cq + mq) % 17;    // granule swizzle: bank step 10 mod 32
        *(uint2*)(&sT[(m0 + 0) * TROW + p * 4]) = pack4(v0.x, v1.x, v2.x, v3.x);
        *(uint2*)(&sT[(m0 + 1) * TROW + p * 4]) = pack4(v0.y, v1.y, v2.y, v3.y);
        *(uint2*)(&sT[(m0 + 2) * TROW + p * 4]) = pack4(v0.z, v1.z, v2.z, v3.z);
        *(uint2*)(&sT[(m0 + 3) * TROW + p * 4]) = pack4(v0.w, v1.w, v2.w, v3.w);
    }
    __syncthreads();

    // Phase B: coalesced 16B stores of [hw][64c] rows
    unsigned short* Xb = Xt + ((size_t)(b * 8 + kk) * HW + hw_base) * BK;
    #pragma unroll
    for (int e0 = 0; e0 < 2; ++e0) {
        int ch = t + e0 * 448;            // 896 chunks
        int m = ch >> 3, j = ch & 7;
        int q4 = m >> 2;
        int p0 = (2 * j + q4) % 17;
        int p1 = (2 * j + 1 + q4) % 17;
        uint2 a = *(const uint2*)(&sT[m * TROW + p0 * 4]);
        uint2 c = *(const uint2*)(&sT[m * TROW + p1 * 4]);
        uint4 v; v.x = a.x; v.y = a.y; v.z = c.x; v.w = c.y;
        *(uint4*)(Xb + (size_t)m * BK + j * 8) = v;   // regular store: keep Xt L2/L3-hot
    }
}

// ---------------- Pass 2: GEMM o-tile 256, W reg-streamed 2-deep, X dbuf via glds ----------------
// 256 thr / 4 waves; wave = 64o x 112hw (acc[4][7] = 112 AGPR). 56 MFMA per wave per
// k-step against the same 14 KiB staged -> 2x compute/stage ratio vs o-tile 128.
__global__ __launch_bounds__(256, 2)
void p2_gemm(const unsigned short* __restrict__ Wb, const unsigned short* __restrict__ Xt,
             const float* __restrict__ gamma, const float* __restrict__ beta,
             const float* __restrict__ rmean, const float* __restrict__ rvar,
             float* __restrict__ out)
{
    __shared__ unsigned short sX[2][MT * BK];   // 2 x 14336 B

    const int t  = threadIdx.x;
    // XCD-pairing swizzle: the 2 o-halves of one X-slab at ids {base, base+8}
    const int id   = blockIdx.x;                 // 0..895
    const int ot   = (id >> 3) & 1;
    const int pair = ((id >> 4) << 3) | (id & 7);   // 0..447
    const int mt   = pair % 7;
    const int b    = pair / 7;
    const int o_base  = ot * 256;
    const int hw_base = mt * MT;
    const int lane = t & 63;
    const int wv   = t >> 6;
    const int m16  = lane & 15;
    const int q    = lane >> 4;

    const unsigned short* Xbase = Xt + ((size_t)(b * 8) * HW + hw_base) * BK;

    auto stage = [&](int kk, int bufi) {
        unsigned short* buf = sX[bufi];
        const unsigned short* Xk = Xbase + (size_t)kk * HW * BK;
        int nci = (wv < 2) ? 4 : 3;
        for (int i = 0; i < nci; ++i) {
            int ci = wv + 4 * i;
            int ch = ci * 64 + lane;
            int hl = ch >> 3, sl = ch & 7;
            int cs = sl ^ (hl & 7);
            gl_lds16(Xk + hl * BK + cs * 8, &buf[ci * 512]);
        }
    };

    // per-wave W row pointers (bo = 0..3), k offset in ushorts
    const unsigned short* wr0 = Wb + (size_t)(o_base + wv * 64 + m16) * CIN + q * 8;
    const unsigned short* wr1 = wr0 + 16 * CIN;
    const unsigned short* wr2 = wr0 + 32 * CIN;
    const unsigned short* wr3 = wr0 + 48 * CIN;

    f32x4 acc[4][7];
    #pragma unroll
    for (int i = 0; i < 4; ++i)
        #pragma unroll
        for (int j = 0; j < 7; ++j)
            acc[i][j] = (f32x4){0.f, 0.f, 0.f, 0.f};

    short8 wc[2][4], wn[2][4];   // [ks][bo] current / next
#define LOADW(DST, KK)                                  \
    {   const int ko = (KK) * 64;                       \
        DST[0][0] = *(const short8*)(wr0 + ko);         \
        DST[0][1] = *(const short8*)(wr1 + ko);         \
        DST[0][2] = *(const short8*)(wr2 + ko);         \
        DST[0][3] = *(const short8*)(wr3 + ko);         \
        DST[1][0] = *(const short8*)(wr0 + ko + 32);    \
        DST[1][1] = *(const short8*)(wr1 + ko + 32);    \
        DST[1][2] = *(const short8*)(wr2 + ko + 32);    \
        DST[1][3] = *(const short8*)(wr3 + ko + 32);    \
    }

#define MFMA16(A, B, C) __builtin_amdgcn_mfma_f32_16x16x32_bf16((A), (B), (C), 0, 0, 0)
#define COMPUTE(XS, WF)                                                          \
    {                                                                            \
        const unsigned short* xs = (XS);                                         \
        _Pragma("unroll")                                                        \
        for (int ks = 0; ks < 2; ++ks) {                                         \
            _Pragma("unroll")                                                    \
            for (int bm = 0; bm < 7; ++bm) {                                     \
                int m  = bm * 16 + m16;                                          \
                int lc = ks * 4 + q;                                             \
                int sl = lc ^ (m & 7);                                           \
                short8 bf = *(const short8*)(&xs[m * BK + sl * 8]);              \
                acc[0][bm] = MFMA16(WF[ks][0], bf, acc[0][bm]);                  \
                acc[1][bm] = MFMA16(WF[ks][1], bf, acc[1][bm]);                  \
                acc[2][bm] = MFMA16(WF[ks][2], bf, acc[2][bm]);                  \
                acc[3][bm] = MFMA16(WF[ks][3], bf, acc[3][bm]);                  \
            }                                                                    \
        }                                                                        \
    }

    stage(0, 0);
    LOADW(wc, 0);
    __syncthreads();   // sX[0] ready

    #pragma unroll 1
    for (int kp = 0; kp < 4; ++kp) {
        {   // kk = 2*kp (even) -> compute buf0, prefetch buf1 + wn
            const int kn = 2 * kp + 1;
            stage(kn, 1);
            LOADW(wn, kn);
            COMPUTE(sX[0], wc);
            __syncthreads();
        }
        {   // kk = 2*kp+1 (odd) -> compute buf1, prefetch buf0 + wc
            const int kn = 2 * kp + 2;
            if (kn < NKB) {
                stage(kn, 0);
                LOADW(wc, kn);
            }
            COMPUTE(sX[1], wn);
            __syncthreads();
        }
    }
#undef COMPUTE
#undef MFMA16
#undef LOADW

    float scl[4][4], shf[4][4];
    #pragma unroll
    for (int bo = 0; bo < 4; ++bo)
        #pragma unroll
        for (int r = 0; r < 4; ++r) {
            int o = o_base + wv * 64 + bo * 16 + q * 4 + r;
            float sc = gamma[o] * rsqrtf(rvar[o] + 1e-5f);
            scl[bo][r] = sc;
            shf[bo][r] = beta[o] - rmean[o] * sc;
        }
    float* outb = out + (size_t)b * COUT * HW;
    #pragma unroll
    for (int bo = 0; bo < 4; ++bo) {
        #pragma unroll
        for (int r = 0; r < 4; ++r) {
            int o = o_base + wv * 64 + bo * 16 + q * 4 + r;
            float* orow = outb + (size_t)o * HW + hw_base + m16;
            #pragma unroll
            for (int bm = 0; bm < 7; ++bm) {
                float y = acc[bo][bm][r] * scl[bo][r] + shf[bo][r];
                y = fmaxf(y, 0.f);
                __builtin_nontemporal_store(y, orow + bm * 16);
            }
        }
    }
}

// ---------------- Fallback (ws too small): round-1 single-pass ----------------
#define SW_STRIDE 72
#define SX_STRIDE 64
__global__ __launch_bounds__(256, 2)
void shiftconv_fallback(const float* __restrict__ x, const float* __restrict__ Wf,
                        const float* __restrict__ gamma, const float* __restrict__ beta,
                        const float* __restrict__ rmean, const float* __restrict__ rvar,
                        float* __restrict__ out)
{
    __shared__ unsigned short sW[NT * SW_STRIDE];
    __shared__ unsigned short sX[MT * SX_STRIDE];
    const int t = threadIdx.x;
    const int ot = blockIdx.x, mt = blockIdx.y, b = blockIdx.z;
    const int o_base = ot * NT, hw_base = mt * MT;
    const float* xb = x + (size_t)b * CIN * HW;
    const int lane = t & 63, wv = t >> 6, m16 = lane & 15, q = lane >> 4;
    f32x4 acc[2][7];
    #pragma unroll
    for (int i = 0; i < 2; ++i)
        #pragma unroll
        for (int j = 0; j < 7; ++j) acc[i][j] = (f32x4){0.f, 0.f, 0.f, 0.f};
    #pragma unroll
    for (int kk = 0; kk < CIN / BK; ++kk) {
        const int k0 = kk * BK;
        const int g = k0 >> 7;
        #pragma unroll
        for (int e0 = 0; e0 < 2; ++e0) {
            int e = t + e0 * 256;
            if (e < (BK / 4) * (MT / 4)) {
                int cq = e / 28, mq = e - cq * 28;
                int hw = hw_base + mq * 4;
                const float* src = xb + (size_t)(k0 + cq * 4) * HW;
                float4 v0, v1, v2, v3;
                if (g < 2) {
                    int shw = hw + (g == 0 ? 28 : HW - 28);
                    if (shw >= HW) shw -= HW;
                    v0 = *(const float4*)(src + 0 * HW + shw);
                    v1 = *(const float4*)(src + 1 * HW + shw);
                    v2 = *(const float4*)(src + 2 * HW + shw);
                    v3 = *(const float4*)(src + 3 * HW + shw);
                } else {
                    int h = hw / 28, w0 = hw - h * 28, base = h * 28;
                    #pragma unroll
                    for (int j = 0; j < 4; ++j) {
                        const float* row = src + j * HW + base;
                        float4 a = *(const float4*)(row + w0);
                        float4 r;
                        if (g == 2) {
                            float ex = row[(w0 + 4 < 28) ? (w0 + 4) : 0];
                            r.x = a.y; r.y = a.z; r.z = a.w; r.w = ex;
                        } else {
                            float ex = row[(w0 == 0) ? 27 : (w0 - 1)];
                            r.x = ex; r.y = a.x; r.z = a.y; r.w = a.z;
                        }
                        if (j == 0) v0 = r; else if (j == 1) v1 = r;
                        else if (j == 2) v2 = r; else v3 = r;
                    }
                }
                int m0 = mq * 4;
                { int p = (cq + 5 * (m0 + 0)) & 15;
                  *(uint2*)(&sX[(m0 + 0) * SX_STRIDE + p * 4]) = pack4(v0.x, v1.x, v2.x, v3.x); }
                { int p = (cq + 5 * (m0 + 1)) & 15;
                  *(uint2*)(&sX[(m0 + 1) * SX_STRIDE + p * 4]) = pack4(v0.y, v1.y, v2.y, v3.y); }
                { int p = (cq + 5 * (m0 + 2)) & 15;
                  *(uint2*)(&sX[(m0 + 2) * SX_STRIDE + p * 4]) = pack4(v0.z, v1.z, v2.z, v3.z); }
                { int p = (cq + 5 * (m0 + 3)) & 15;
                  *(uint2*)(&sX[(m0 + 3) * SX_STRIDE + p * 4]) = pack4(v0.w, v1.w, v2.w, v3.w); }
            }
        }
        #pragma unroll
        for (int i = 0; i < 4; ++i) {
            int e = t + i * 256;
            int ol = e >> 3, kg = (e & 7) * 8;
            const float* wr = Wf + (size_t)(o_base + ol) * CIN + k0 + kg;
            float4 a = *(const float4*)(wr);
            float4 c = *(const float4*)(wr + 4);
            uint2 lo = pack4(a.x, a.y, a.z, a.w);
            uint2 hi = pack4(c.x, c.y, c.z, c.w);
            uint4 v; v.x = lo.x; v.y = lo.y; v.z = hi.x; v.w = hi.y;
            *(uint4*)(&sW[ol * SW_STRIDE + kg]) = v;
        }
        __syncthreads();
        #pragma unroll
        for (int ks = 0; ks < BK; ks += 32) {
            short8 afrag[2];
            #pragma unroll
            for (int bo = 0; bo < 2; ++bo) {
                int row = wv * 32 + bo * 16 + m16;
                afrag[bo] = *(const short8*)(&sW[row * SW_STRIDE + ks + q * 8]);
            }
            #pragma unroll
            for (int bm = 0; bm < 7; ++bm) {
                int m = bm * 16 + m16;
                int g0 = (ks >> 2) + 2 * q;
                int p0 = (g0 + 5 * m) & 15;
                int p1 = (g0 + 1 + 5 * m) & 15;
                uint2 lo = *(const uint2*)(&sX[m * SX_STRIDE + p0 * 4]);
                uint2 hi = *(const uint2*)(&sX[m * SX_STRIDE + p1 * 4]);
                union { uint2 u2[2]; short8 s; } fb;
                fb.u2[0] = lo; fb.u2[1] = hi;
                acc[0][bm] = __builtin_amdgcn_mfma_f32_16x16x32_bf16(afrag[0], fb.s, acc[0][bm], 0, 0, 0);
                acc[1][bm] = __builtin_amdgcn_mfma_f32_16x16x32_bf16(afrag[1], fb.s, acc[1][bm], 0, 0, 0);
            }
        }
        __syncthreads();
    }
    float scl[2][4], shf[2][4];
    #pragma unroll
    for (int bo = 0; bo < 2; ++bo)
        #pragma unroll
        for (int r = 0; r < 4; ++r) {
            int o = o_base + wv * 32 + bo * 16 + q * 4 + r;
            float sc = gamma[o] * rsqrtf(rvar[o] + 1e-5f);
            scl[bo][r] = sc;
            shf[bo][r] = beta[o] - rmean[o] * sc;
        }
    float* outb = out + (size_t)b * COUT * HW;
    #pragma unroll
    for (int bo = 0; bo < 2; ++bo)
        #pragma unroll
        for (int r = 0; r < 4; ++r) {
            int o = o_base + wv * 32 + bo * 16 + q * 4 + r;
            float* orow = outb + (size_t)o * HW + hw_base + m16;
            #pragma unroll
            for (int bm = 0; bm < 7; ++bm) {
                float y = acc[bo][bm][r] * scl[bo][r] + shf[bo][r];
                y = fmaxf(y, 0.f);
                __builtin_nontemporal_store(y, orow + bm * 16);
            }
        }
}

extern "C" void kernel_launch(void* const* d_in, const int* in_sizes, int n_in,
                              void* d_out, int out_size, void* d_ws, size_t ws_size,
                              hipStream_t stream)
{
    const float* x     = (const float*)d_in[0];
    const float* W     = (const float*)d_in[1];
    const float* gamma = (const float*)d_in[2];
    const float* beta  = (const float*)d_in[3];
    const float* rmean = (const float*)d_in[4];
    const float* rvar  = (const float*)d_in[5];
    float* out = (float*)d_out;

    const size_t wb_bytes = (size_t)COUT * CIN * 2;                 // 512 KB
    const size_t xt_bytes = (size_t)BN * CIN * HW * 2;              // ~51.4 MB
    if (ws_size >= wb_bytes + xt_bytes) {
        unsigned short* Wb = (unsigned short*)d_ws;
        unsigned short* Xt = (unsigned short*)((char*)d_ws + wb_bytes);
        dim3 g1(8, 7, BN + 1);
        p1_shift_cvt<<<g1, 448, 0, stream>>>(x, W, Wb, Xt);
        p2_gemm<<<896, 256, 0, stream>>>(Wb, Xt, gamma, beta, rmean, rvar, out);
    } else {
        dim3 grid(COUT / NT, HW / MT, BN);
        shiftconv_fallback<<<grid, 256, 0, stream>>>(x, W, gamma, beta, rmean, rvar, out);
    }
}

// Round 7
// 230.018 us; speedup vs baseline: 2.8913x; 1.0095x over previous
//
#include <hip/hip_runtime.h>

#define BN   64
#define CIN  512
#define COUT 512
#define HW   784
#define NT   128      /* fallback o-tile */
#define MT   112
#define BK   64
#define NKB  (CIN / BK)
#define TROW 68   /* 17 granules x 8B = 136 B rows */

typedef __attribute__((ext_vector_type(8))) short short8;
typedef __attribute__((ext_vector_type(4))) float f32x4;

__device__ __forceinline__ unsigned short f2bf(float f) {
    union { float f; unsigned int u; } v; v.f = f;
    unsigned int r = v.u + 0x7fffu + ((v.u >> 16) & 1u);   // RNE
    return (unsigned short)(r >> 16);
}

__device__ __forceinline__ uint2 pack4(float a, float b, float c, float d) {
    uint2 r;
    r.x = (unsigned int)f2bf(a) | ((unsigned int)f2bf(b) << 16);
    r.y = (unsigned int)f2bf(c) | ((unsigned int)f2bf(d) << 16);
    return r;
}

__device__ __forceinline__ void gl_lds16(const unsigned short* g, unsigned short* l) {
    __builtin_amdgcn_global_load_lds(
        (const __attribute__((address_space(1))) unsigned int*)g,
        (__attribute__((address_space(3))) unsigned int*)l,
        16, 0, 0);
}

// ---------------- Pass 1: shift + cvt + LDS transpose (mod-17 swizzle) ----------------
// grid (8, 7, 65), 448 threads; z==64 blocks convert W -> bf16.
__global__ __launch_bounds__(448)
void p1_shift_cvt(const float* __restrict__ x, const float* __restrict__ W,
                  unsigned short* __restrict__ Wb, unsigned short* __restrict__ Xt)
{
    __shared__ unsigned short sT[MT * TROW];   // 15232 B
    const int t = threadIdx.x;
    if (blockIdx.z == BN) {
        int wlin = blockIdx.x * 7 + blockIdx.y;           // 0..55
        for (int gi = wlin * 448 + t; gi < (COUT * CIN) / 8; gi += 56 * 448) {
            const float* p = W + (size_t)gi * 8;
            float4 a = *(const float4*)p;
            float4 c = *(const float4*)(p + 4);
            uint2 lo = pack4(a.x, a.y, a.z, a.w);
            uint2 hi = pack4(c.x, c.y, c.z, c.w);
            uint4 v; v.x = lo.x; v.y = lo.y; v.z = hi.x; v.w = hi.y;
            *(uint4*)(Wb + (size_t)gi * 8) = v;
        }
        return;
    }
    const int kk = blockIdx.x;            // c-block of 64
    const int mt = blockIdx.y;            // hw-tile of 112
    const int b  = blockIdx.z;
    const int g  = kk >> 1;               // shift group (block-uniform)
    const int c0 = kk * BK;
    const int hw_base = mt * MT;
    const float* xb = x + (size_t)b * CIN * HW;

    // Phase A: one 4c x 4hw micro-tile per lane (448 items, 448 lanes)
    {
        const int cq = t / 28;            // 0..15
        const int mq = t - cq * 28;       // 0..27
        const int hw = hw_base + mq * 4;
        const float* src = xb + (size_t)(c0 + cq * 4) * HW;
        float4 v0, v1, v2, v3;
        if (g < 2) {
            int shw = hw + (g == 0 ? 28 : HW - 28);
            if (shw >= HW) shw -= HW;
            v0 = *(const float4*)(src + 0 * HW + shw);
            v1 = *(const float4*)(src + 1 * HW + shw);
            v2 = *(const float4*)(src + 2 * HW + shw);
            v3 = *(const float4*)(src + 3 * HW + shw);
        } else {
            int h  = hw / 28;
            int w0 = hw - h * 28;
            int base = h * 28;
            #pragma unroll
            for (int j = 0; j < 4; ++j) {
                const float* row = src + j * HW + base;
                float4 a = *(const float4*)(row + w0);
                float4 r;
                if (g == 2) {
                    float ex = row[(w0 + 4 < 28) ? (w0 + 4) : 0];
                    r.x = a.y; r.y = a.z; r.z = a.w; r.w = ex;
                } else {
                    float ex = row[(w0 == 0) ? 27 : (w0 - 1)];
                    r.x = ex; r.y = a.x; r.z = a.y; r.w = a.z;
                }
                if (j == 0) v0 = r; else if (j == 1) v1 = r;
                else if (j == 2) v2 = r; else v3 = r;
            }
        }
        const int m0 = mq * 4;
        const int p  = (cq + mq) % 17;    // granule swizzle: bank step 10 mod 32
        *(uint2*)(&sT[(m0 + 0) * TROW + p * 4]) = pack4(v0.x, v1.x, v2.x, v3.x);
        *(uint2*)(&sT[(m0 + 1) * TROW + p * 4]) = pack4(v0.y, v1.y, v2.y, v3.y);
        *(uint2*)(&sT[(m0 + 2) * TROW + p * 4]) = pack4(v0.z, v1.z, v2.z, v3.z);
        *(uint2*)(&sT[(m0 + 3) * TROW + p * 4]) = pack4(v0.w, v1.w, v2.w, v3.w);
    }
    __syncthreads();

    // Phase B: coalesced 16B stores of [hw][64c] rows
    unsigned short* Xb = Xt + ((size_t)(b * 8 + kk) * HW + hw_base) * BK;
    #pragma unroll
    for (int e0 = 0; e0 < 2; ++e0) {
        int ch = t + e0 * 448;            // 896 chunks
        int m = ch >> 3, j = ch & 7;
        int q4 = m >> 2;
        int p0 = (2 * j + q4) % 17;
        int p1 = (2 * j + 1 + q4) % 17;
        uint2 a = *(const uint2*)(&sT[m * TROW + p0 * 4]);
        uint2 c = *(const uint2*)(&sT[m * TROW + p1 * 4]);
        uint4 v; v.x = a.x; v.y = a.y; v.z = c.x; v.w = c.y;
        *(uint4*)(Xb + (size_t)m * BK + j * 8) = v;   // regular store: keep Xt L2/L3-hot
    }
}

// ---------------- Pass 2: GEMM o-tile 256, counted-vmcnt 2-deep pipeline ----------------
// 256 thr / 4 waves; wave = 64o x 112hw (acc[4][7]). 4-buffer LDS ring; staging issued
// 2 k-steps ahead; raw s_barrier + counted s_waitcnt so prefetch loads stay in flight
// ACROSS barriers (T3/T4). FIFO per phase: LOADW(k+1) [8] then stage(k+2) [4 or 3];
// end-of-phase keep = 12 (wv<2) / 11 (wv>=2) retires exactly stage(k+1).
__global__ __launch_bounds__(256, 2)
void p2_gemm(const unsigned short* __restrict__ Wb, const unsigned short* __restrict__ Xt,
             const float* __restrict__ gamma, const float* __restrict__ beta,
             const float* __restrict__ rmean, const float* __restrict__ rvar,
             float* __restrict__ out)
{
    __shared__ unsigned short sX[4][MT * BK];   // 4 x 14336 B ring

    const int t  = threadIdx.x;
    // XCD-pairing swizzle: the 2 o-halves of one X-slab at ids {base, base+8}
    const int id   = blockIdx.x;                 // 0..895
    const int ot   = (id >> 3) & 1;
    const int pair = ((id >> 4) << 3) | (id & 7);   // 0..447
    const int mt   = pair % 7;
    const int b    = pair / 7;
    const int o_base  = ot * 256;
    const int hw_base = mt * MT;
    const int lane = t & 63;
    const int wv   = t >> 6;
    const int m16  = lane & 15;
    const int q    = lane >> 4;

    const unsigned short* Xbase = Xt + ((size_t)(b * 8) * HW + hw_base) * BK;

    auto stage = [&](int kk, int bufi) {
        unsigned short* buf = sX[bufi];
        const unsigned short* Xk = Xbase + (size_t)kk * HW * BK;
        const int nci = (wv < 2) ? 4 : 3;
        for (int i = 0; i < nci; ++i) {
            int ci = wv + 4 * i;
            int ch = ci * 64 + lane;
            int hl = ch >> 3, sl = ch & 7;
            int cs = sl ^ (hl & 7);
            gl_lds16(Xk + hl * BK + cs * 8, &buf[ci * 512]);
        }
    };

    // per-wave W row pointers (bo = 0..3), k offset in ushorts
    const unsigned short* wr0 = Wb + (size_t)(o_base + wv * 64 + m16) * CIN + q * 8;
    const unsigned short* wr1 = wr0 + 16 * CIN;
    const unsigned short* wr2 = wr0 + 32 * CIN;
    const unsigned short* wr3 = wr0 + 48 * CIN;

    f32x4 acc[4][7];
    #pragma unroll
    for (int i = 0; i < 4; ++i)
        #pragma unroll
        for (int j = 0; j < 7; ++j)
            acc[i][j] = (f32x4){0.f, 0.f, 0.f, 0.f};

    short8 wc[2][4], wn[2][4];   // [ks][bo] alternating W prefetch sets
#define LOADW(DST, KK)                                  \
    {   const int ko = (KK) * 64;                       \
        DST[0][0] = *(const short8*)(wr0 + ko);         \
        DST[0][1] = *(const short8*)(wr1 + ko);         \
        DST[0][2] = *(const short8*)(wr2 + ko);         \
        DST[0][3] = *(const short8*)(wr3 + ko);         \
        DST[1][0] = *(const short8*)(wr0 + ko + 32);    \
        DST[1][1] = *(const short8*)(wr1 + ko + 32);    \
        DST[1][2] = *(const short8*)(wr2 + ko + 32);    \
        DST[1][3] = *(const short8*)(wr3 + ko + 32);    \
    }

#define MFMA16(A, B, C) __builtin_amdgcn_mfma_f32_16x16x32_bf16((A), (B), (C), 0, 0, 0)
#define COMPUTE(XS, WF)                                                          \
    {                                                                            \
        const unsigned short* xs = (XS);                                         \
        _Pragma("unroll")                                                        \
        for (int ks = 0; ks < 2; ++ks) {                                         \
            _Pragma("unroll")                                                    \
            for (int bm = 0; bm < 7; ++bm) {                                     \
                int m  = bm * 16 + m16;                                          \
                int lc = ks * 4 + q;                                             \
                int sl = lc ^ (m & 7);                                           \
                short8 bf = *(const short8*)(&xs[m * BK + sl * 8]);              \
                acc[0][bm] = MFMA16(WF[ks][0], bf, acc[0][bm]);                  \
                acc[1][bm] = MFMA16(WF[ks][1], bf, acc[1][bm]);                  \
                acc[2][bm] = MFMA16(WF[ks][2], bf, acc[2][bm]);                  \
                acc[3][bm] = MFMA16(WF[ks][3], bf, acc[3][bm]);                  \
            }                                                                    \
        }                                                                        \
    }

    // counted barrier: keep only this phase's issues in flight, then raw s_barrier.
#define BARC(K12, K11)                                                           \
    {   __builtin_amdgcn_sched_barrier(0);                                       \
        if (wv < 2) asm volatile("s_waitcnt vmcnt(" #K12 ")" ::: "memory");      \
        else        asm volatile("s_waitcnt vmcnt(" #K11 ")" ::: "memory");      \
        __builtin_amdgcn_s_barrier();                                            \
        __builtin_amdgcn_sched_barrier(0);                                       \
    }

    // ---- prologue: FIFO = stage0 | W0 | stage1 ; retire stage0, keep W0+stage1 ----
    stage(0, 0);
    LOADW(wc, 0);
    stage(1, 1);
    BARC(12, 11);

    // ---- steady phases: LOADW(k+1) ; stage(k+2) ; COMPUTE(k) ; counted bar ----
#define PHASE(K, WCUR, WNXT)                    \
    LOADW(WNXT, (K) + 1);                       \
    stage((K) + 2, ((K) + 2) & 3);              \
    COMPUTE(sX[(K) & 3], WCUR);                 \
    BARC(12, 11);

    PHASE(0, wc, wn)
    PHASE(1, wn, wc)
    PHASE(2, wc, wn)
    PHASE(3, wn, wc)
    PHASE(4, wc, wn)
    PHASE(5, wn, wc)
    // phase 6: no stage left; keep only W7 (8)
    LOADW(wn, 7);
    COMPUTE(sX[2], wc);
    BARC(8, 8);
    // phase 7: pure compute
    COMPUTE(sX[3], wn);
#undef PHASE
#undef BARC
#undef COMPUTE
#undef MFMA16
#undef LOADW

    float scl[4][4], shf[4][4];
    #pragma unroll
    for (int bo = 0; bo < 4; ++bo)
        #pragma unroll
        for (int r = 0; r < 4; ++r) {
            int o = o_base + wv * 64 + bo * 16 + q * 4 + r;
            float sc = gamma[o] * rsqrtf(rvar[o] + 1e-5f);
            scl[bo][r] = sc;
            shf[bo][r] = beta[o] - rmean[o] * sc;
        }
    float* outb = out + (size_t)b * COUT * HW;
    #pragma unroll
    for (int bo = 0; bo < 4; ++bo) {
        #pragma unroll
        for (int r = 0; r < 4; ++r) {
            int o = o_base + wv * 64 + bo * 16 + q * 4 + r;
            float* orow = outb + (size_t)o * HW + hw_base + m16;
            #pragma unroll
            for (int bm = 0; bm < 7; ++bm) {
                float y = acc[bo][bm][r] * scl[bo][r] + shf[bo][r];
                y = fmaxf(y, 0.f);
                __builtin_nontemporal_store(y, orow + bm * 16);
            }
        }
    }
}

// ---------------- Fallback (ws too small): round-1 single-pass ----------------
#define SW_STRIDE 72
#define SX_STRIDE 64
__global__ __launch_bounds__(256, 2)
void shiftconv_fallback(const float* __restrict__ x, const float* __restrict__ Wf,
                        const float* __restrict__ gamma, const float* __restrict__ beta,
                        const float* __restrict__ rmean, const float* __restrict__ rvar,
                        float* __restrict__ out)
{
    __shared__ unsigned short sW[NT * SW_STRIDE];
    __shared__ unsigned short sX[MT * SX_STRIDE];
    const int t = threadIdx.x;
    const int ot = blockIdx.x, mt = blockIdx.y, b = blockIdx.z;
    const int o_base = ot * NT, hw_base = mt * MT;
    const float* xb = x + (size_t)b * CIN * HW;
    const int lane = t & 63, wv = t >> 6, m16 = lane & 15, q = lane >> 4;
    f32x4 acc[2][7];
    #pragma unroll
    for (int i = 0; i < 2; ++i)
        #pragma unroll
        for (int j = 0; j < 7; ++j) acc[i][j] = (f32x4){0.f, 0.f, 0.f, 0.f};
    #pragma unroll
    for (int kk = 0; kk < CIN / BK; ++kk) {
        const int k0 = kk * BK;
        const int g = k0 >> 7;
        #pragma unroll
        for (int e0 = 0; e0 < 2; ++e0) {
            int e = t + e0 * 256;
            if (e < (BK / 4) * (MT / 4)) {
                int cq = e / 28, mq = e - cq * 28;
                int hw = hw_base + mq * 4;
                const float* src = xb + (size_t)(k0 + cq * 4) * HW;
                float4 v0, v1, v2, v3;
                if (g < 2) {
                    int shw = hw + (g == 0 ? 28 : HW - 28);
                    if (shw >= HW) shw -= HW;
                    v0 = *(const float4*)(src + 0 * HW + shw);
                    v1 = *(const float4*)(src + 1 * HW + shw);
                    v2 = *(const float4*)(src + 2 * HW + shw);
                    v3 = *(const float4*)(src + 3 * HW + shw);
                } else {
                    int h = hw / 28, w0 = hw - h * 28, base = h * 28;
                    #pragma unroll
                    for (int j = 0; j < 4; ++j) {
                        const float* row = src + j * HW + base;
                        float4 a = *(const float4*)(row + w0);
                        float4 r;
                        if (g == 2) {
                            float ex = row[(w0 + 4 < 28) ? (w0 + 4) : 0];
                            r.x = a.y; r.y = a.z; r.z = a.w; r.w = ex;
                        } else {
                            float ex = row[(w0 == 0) ? 27 : (w0 - 1)];
                            r.x = ex; r.y = a.x; r.z = a.y; r.w = a.z;
                        }
                        if (j == 0) v0 = r; else if (j == 1) v1 = r;
                        else if (j == 2) v2 = r; else v3 = r;
                    }
                }
                int m0 = mq * 4;
                { int p = (cq + 5 * (m0 + 0)) & 15;
                  *(uint2*)(&sX[(m0 + 0) * SX_STRIDE + p * 4]) = pack4(v0.x, v1.x, v2.x, v3.x); }
                { int p = (cq + 5 * (m0 + 1)) & 15;
                  *(uint2*)(&sX[(m0 + 1) * SX_STRIDE + p * 4]) = pack4(v0.y, v1.y, v2.y, v3.y); }
                { int p = (cq + 5 * (m0 + 2)) & 15;
                  *(uint2*)(&sX[(m0 + 2) * SX_STRIDE + p * 4]) = pack4(v0.z, v1.z, v2.z, v3.z); }
                { int p = (cq + 5 * (m0 + 3)) & 15;
                  *(uint2*)(&sX[(m0 + 3) * SX_STRIDE + p * 4]) = pack4(v0.w, v1.w, v2.w, v3.w); }
            }
        }
        #pragma unroll
        for (int i = 0; i < 4; ++i) {
            int e = t + i * 256;
            int ol = e >> 3, kg = (e & 7) * 8;
            const float* wr = Wf + (size_t)(o_base + ol) * CIN + k0 + kg;
            float4 a = *(const float4*)(wr);
            float4 c = *(const float4*)(wr + 4);
            uint2 lo = pack4(a.x, a.y, a.z, a.w);
            uint2 hi = pack4(c.x, c.y, c.z, c.w);
            uint4 v; v.x = lo.x; v.y = lo.y; v.z = hi.x; v.w = hi.y;
            *(uint4*)(&sW[ol * SW_STRIDE + kg]) = v;
        }
        __syncthreads();
        #pragma unroll
        for (int ks = 0; ks < BK; ks += 32) {
            short8 afrag[2];
            #pragma unroll
            for (int bo = 0; bo < 2; ++bo) {
                int row = wv * 32 + bo * 16 + m16;
                afrag[bo] = *(const short8*)(&sW[row * SW_STRIDE + ks + q * 8]);
            }
            #pragma unroll
            for (int bm = 0; bm < 7; ++bm) {
                int m = bm * 16 + m16;
                int g0 = (ks >> 2) + 2 * q;
                int p0 = (g0 + 5 * m) & 15;
                int p1 = (g0 + 1 + 5 * m) & 15;
                uint2 lo = *(const uint2*)(&sX[m * SX_STRIDE + p0 * 4]);
                uint2 hi = *(const uint2*)(&sX[m * SX_STRIDE + p1 * 4]);
                union { uint2 u2[2]; short8 s; } fb;
                fb.u2[0] = lo; fb.u2[1] = hi;
                acc[0][bm] = __builtin_amdgcn_mfma_f32_16x16x32_bf16(afrag[0], fb.s, acc[0][bm], 0, 0, 0);
                acc[1][bm] = __builtin_amdgcn_mfma_f32_16x16x32_bf16(afrag[1], fb.s, acc[1][bm], 0, 0, 0);
            }
        }
        __syncthreads();
    }
    float scl[2][4], shf[2][4];
    #pragma unroll
    for (int bo = 0; bo < 2; ++bo)
        #pragma unroll
        for (int r = 0; r < 4; ++r) {
            int o = o_base + wv * 32 + bo * 16 + q * 4 + r;
            float sc = gamma[o] * rsqrtf(rvar[o] + 1e-5f);
            scl[bo][r] = sc;
            shf[bo][r] = beta[o] - rmean[o] * sc;
        }
    float* outb = out + (size_t)b * COUT * HW;
    #pragma unroll
    for (int bo = 0; bo < 2; ++bo)
        #pragma unroll
        for (int r = 0; r < 4; ++r) {
            int o = o_base + wv * 32 + bo * 16 + q * 4 + r;
            float* orow = outb + (size_t)o * HW + hw_base + m16;
            #pragma unroll
            for (int bm = 0; bm < 7; ++bm) {
                float y = acc[bo][bm][r] * scl[bo][r] + shf[bo][r];
                y = fmaxf(y, 0.f);
                __builtin_nontemporal_store(y, orow + bm * 16);
            }
        }
}

extern "C" void kernel_launch(void* const* d_in, const int* in_sizes, int n_in,
                              void* d_out, int out_size, void* d_ws, size_t ws_size,
                              hipStream_t stream)
{
    const float* x     = (const float*)d_in[0];
    const float* W     = (const float*)d_in[1];
    const float* gamma = (const float*)d_in[2];
    const float* beta  = (const float*)d_in[3];
    const float* rmean = (const float*)d_in[4];
    const float* rvar  = (const float*)d_in[5];
    float* out = (float*)d_out;

    const size_t wb_bytes = (size_t)COUT * CIN * 2;                 // 512 KB
    const size_t xt_bytes = (size_t)BN * CIN * HW * 2;              // ~51.4 MB
    if (ws_size >= wb_bytes + xt_bytes) {
        unsigned short* Wb = (unsigned short*)d_ws;
        unsigned short* Xt = (unsigned short*)((char*)d_ws + wb_bytes);
        dim3 g1(8, 7, BN + 1);
        p1_shift_cvt<<<g1, 448, 0, stream>>>(x, W, Wb, Xt);
        p2_gemm<<<896, 256, 0, stream>>>(Wb, Xt, gamma, beta, rmean, rvar, out);
    } else {
        dim3 grid(COUT / NT, HW / MT, BN);
        shiftconv_fallback<<<grid, 256, 0, stream>>>(x, W, gamma, beta, rmean, rvar, out);
    }
}

// Round 8
// 228.533 us; speedup vs baseline: 2.9101x; 1.0065x over previous
//
#include <hip/hip_runtime.h>

#define BN   64
#define CIN  512
#define COUT 512
#define HW   784
#define NT   128      /* fallback o-tile */
#define MT   112
#define BK   64
#define NKB  (CIN / BK)
#define TROW 68   /* 17 granules x 8B = 136 B rows */

typedef __attribute__((ext_vector_type(8))) short short8;
typedef __attribute__((ext_vector_type(4))) float f32x4;

__device__ __forceinline__ unsigned short f2bf(float f) {
    union { float f; unsigned int u; } v; v.f = f;
    unsigned int r = v.u + 0x7fffu + ((v.u >> 16) & 1u);   // RNE
    return (unsigned short)(r >> 16);
}

__device__ __forceinline__ uint2 pack4(float a, float b, float c, float d) {
    uint2 r;
    r.x = (unsigned int)f2bf(a) | ((unsigned int)f2bf(b) << 16);
    r.y = (unsigned int)f2bf(c) | ((unsigned int)f2bf(d) << 16);
    return r;
}

__device__ __forceinline__ void gl_lds16(const unsigned short* g, unsigned short* l) {
    __builtin_amdgcn_global_load_lds(
        (const __attribute__((address_space(1))) unsigned int*)g,
        (__attribute__((address_space(3))) unsigned int*)l,
        16, 0, 0);
}

// ---------------- Pass 1: shift + cvt + LDS transpose (mod-17 swizzle) ----------------
// grid (8, 7, 65), 448 threads; z==64 blocks convert W -> bf16.
__global__ __launch_bounds__(448)
void p1_shift_cvt(const float* __restrict__ x, const float* __restrict__ W,
                  unsigned short* __restrict__ Wb, unsigned short* __restrict__ Xt)
{
    __shared__ unsigned short sT[MT * TROW];   // 15232 B
    const int t = threadIdx.x;
    if (blockIdx.z == BN) {
        int wlin = blockIdx.x * 7 + blockIdx.y;           // 0..55
        for (int gi = wlin * 448 + t; gi < (COUT * CIN) / 8; gi += 56 * 448) {
            const float* p = W + (size_t)gi * 8;
            float4 a = *(const float4*)p;
            float4 c = *(const float4*)(p + 4);
            uint2 lo = pack4(a.x, a.y, a.z, a.w);
            uint2 hi = pack4(c.x, c.y, c.z, c.w);
            uint4 v; v.x = lo.x; v.y = lo.y; v.z = hi.x; v.w = hi.y;
            *(uint4*)(Wb + (size_t)gi * 8) = v;
        }
        return;
    }
    const int kk = blockIdx.x;            // c-block of 64
    const int mt = blockIdx.y;            // hw-tile of 112
    const int b  = blockIdx.z;
    const int g  = kk >> 1;               // shift group (block-uniform)
    const int c0 = kk * BK;
    const int hw_base = mt * MT;
    const float* xb = x + (size_t)b * CIN * HW;

    // Phase A: one 4c x 4hw micro-tile per lane (448 items, 448 lanes)
    {
        const int cq = t / 28;            // 0..15
        const int mq = t - cq * 28;       // 0..27
        const int hw = hw_base + mq * 4;
        const float* src = xb + (size_t)(c0 + cq * 4) * HW;
        float4 v0, v1, v2, v3;
        if (g < 2) {
            int shw = hw + (g == 0 ? 28 : HW - 28);
            if (shw >= HW) shw -= HW;
            v0 = *(const float4*)(src + 0 * HW + shw);
            v1 = *(const float4*)(src + 1 * HW + shw);
            v2 = *(const float4*)(src + 2 * HW + shw);
            v3 = *(const float4*)(src + 3 * HW + shw);
        } else {
            int h  = hw / 28;
            int w0 = hw - h * 28;
            int base = h * 28;
            #pragma unroll
            for (int j = 0; j < 4; ++j) {
                const float* row = src + j * HW + base;
                float4 a = *(const float4*)(row + w0);
                float4 r;
                if (g == 2) {
                    float ex = row[(w0 + 4 < 28) ? (w0 + 4) : 0];
                    r.x = a.y; r.y = a.z; r.z = a.w; r.w = ex;
                } else {
                    float ex = row[(w0 == 0) ? 27 : (w0 - 1)];
                    r.x = ex; r.y = a.x; r.z = a.y; r.w = a.z;
                }
                if (j == 0) v0 = r; else if (j == 1) v1 = r;
                else if (j == 2) v2 = r; else v3 = r;
            }
        }
        const int m0 = mq * 4;
        const int p  = (cq + mq) % 17;    // granule swizzle: bank step 10 mod 32
        *(uint2*)(&sT[(m0 + 0) * TROW + p * 4]) = pack4(v0.x, v1.x, v2.x, v3.x);
        *(uint2*)(&sT[(m0 + 1) * TROW + p * 4]) = pack4(v0.y, v1.y, v2.y, v3.y);
        *(uint2*)(&sT[(m0 + 2) * TROW + p * 4]) = pack4(v0.z, v1.z, v2.z, v3.z);
        *(uint2*)(&sT[(m0 + 3) * TROW + p * 4]) = pack4(v0.w, v1.w, v2.w, v3.w);
    }
    __syncthreads();

    // Phase B: coalesced 16B stores of [hw][64c] rows
    unsigned short* Xb = Xt + ((size_t)(b * 8 + kk) * HW + hw_base) * BK;
    #pragma unroll
    for (int e0 = 0; e0 < 2; ++e0) {
        int ch = t + e0 * 448;            // 896 chunks
        int m = ch >> 3, j = ch & 7;
        int q4 = m >> 2;
        int p0 = (2 * j + q4) % 17;
        int p1 = (2 * j + 1 + q4) % 17;
        uint2 a = *(const uint2*)(&sT[m * TROW + p0 * 4]);
        uint2 c = *(const uint2*)(&sT[m * TROW + p1 * 4]);
        uint4 v; v.x = a.x; v.y = a.y; v.z = c.x; v.w = c.y;
        *(uint4*)(Xb + (size_t)m * BK + j * 8) = v;   // regular store: keep Xt L2/L3-hot
    }
}

// ---------------- Pass 2: GEMM o-tile 256, counted-vmcnt 3-deep pipeline + setprio ----------------
// 256 thr / 4 waves; wave = 64o x 112hw (acc[4][7]). 5-buffer LDS ring; staging issued
// 3 k-steps ahead (two full phases of latency cover); raw s_barrier + counted s_waitcnt
// (T3/T4); s_setprio(1) around MFMA cluster (T5). FIFO-derived keeps:
// prologue+P0-4: 16/14, P5: 12/11, P6: 8/8. W-loads retire via backend reg-dep waits.
__global__ __launch_bounds__(256, 2)
void p2_gemm(const unsigned short* __restrict__ Wb, const unsigned short* __restrict__ Xt,
             const float* __restrict__ gamma, const float* __restrict__ beta,
             const float* __restrict__ rmean, const float* __restrict__ rvar,
             float* __restrict__ out)
{
    __shared__ unsigned short sX[5][MT * BK];   // 5 x 14336 B ring

    const int t  = threadIdx.x;
    // XCD-pairing swizzle: the 2 o-halves of one X-slab at ids {base, base+8}
    const int id   = blockIdx.x;                 // 0..895
    const int ot   = (id >> 3) & 1;
    const int pair = ((id >> 4) << 3) | (id & 7);   // 0..447
    const int mt   = pair % 7;
    const int b    = pair / 7;
    const int o_base  = ot * 256;
    const int hw_base = mt * MT;
    const int lane = t & 63;
    const int wv   = t >> 6;
    const int m16  = lane & 15;
    const int q    = lane >> 4;

    const unsigned short* Xbase = Xt + ((size_t)(b * 8) * HW + hw_base) * BK;

    auto stage = [&](int kk, int bufi) {
        unsigned short* buf = sX[bufi];
        const unsigned short* Xk = Xbase + (size_t)kk * HW * BK;
        const int nci = (wv < 2) ? 4 : 3;
        for (int i = 0; i < nci; ++i) {
            int ci = wv + 4 * i;
            int ch = ci * 64 + lane;
            int hl = ch >> 3, sl = ch & 7;
            int cs = sl ^ (hl & 7);
            gl_lds16(Xk + hl * BK + cs * 8, &buf[ci * 512]);
        }
    };

    // per-wave W row pointers (bo = 0..3), k offset in ushorts
    const unsigned short* wr0 = Wb + (size_t)(o_base + wv * 64 + m16) * CIN + q * 8;
    const unsigned short* wr1 = wr0 + 16 * CIN;
    const unsigned short* wr2 = wr0 + 32 * CIN;
    const unsigned short* wr3 = wr0 + 48 * CIN;

    f32x4 acc[4][7];
    #pragma unroll
    for (int i = 0; i < 4; ++i)
        #pragma unroll
        for (int j = 0; j < 7; ++j)
            acc[i][j] = (f32x4){0.f, 0.f, 0.f, 0.f};

    short8 wc[2][4], wn[2][4];   // [ks][bo] alternating W prefetch sets
#define LOADW(DST, KK)                                  \
    {   const int ko = (KK) * 64;                       \
        DST[0][0] = *(const short8*)(wr0 + ko);         \
        DST[0][1] = *(const short8*)(wr1 + ko);         \
        DST[0][2] = *(const short8*)(wr2 + ko);         \
        DST[0][3] = *(const short8*)(wr3 + ko);         \
        DST[1][0] = *(const short8*)(wr0 + ko + 32);    \
        DST[1][1] = *(const short8*)(wr1 + ko + 32);    \
        DST[1][2] = *(const short8*)(wr2 + ko + 32);    \
        DST[1][3] = *(const short8*)(wr3 + ko + 32);    \
    }

#define MFMA16(A, B, C) __builtin_amdgcn_mfma_f32_16x16x32_bf16((A), (B), (C), 0, 0, 0)
#define COMPUTE(XS, WF)                                                          \
    {                                                                            \
        const unsigned short* xs = (XS);                                         \
        __builtin_amdgcn_s_setprio(1);                                           \
        _Pragma("unroll")                                                        \
        for (int ks = 0; ks < 2; ++ks) {                                         \
            _Pragma("unroll")                                                    \
            for (int bm = 0; bm < 7; ++bm) {                                     \
                int m  = bm * 16 + m16;                                          \
                int lc = ks * 4 + q;                                             \
                int sl = lc ^ (m & 7);                                           \
                short8 bf = *(const short8*)(&xs[m * BK + sl * 8]);              \
                acc[0][bm] = MFMA16(WF[ks][0], bf, acc[0][bm]);                  \
                acc[1][bm] = MFMA16(WF[ks][1], bf, acc[1][bm]);                  \
                acc[2][bm] = MFMA16(WF[ks][2], bf, acc[2][bm]);                  \
                acc[3][bm] = MFMA16(WF[ks][3], bf, acc[3][bm]);                  \
            }                                                                    \
        }                                                                        \
        __builtin_amdgcn_s_setprio(0);                                           \
    }

    // counted barrier: keep only still-needed in-flight loads, then raw s_barrier.
#define BARC(K12, K11)                                                           \
    {   __builtin_amdgcn_sched_barrier(0);                                       \
        if (wv < 2) asm volatile("s_waitcnt vmcnt(" #K12 ")" ::: "memory");      \
        else        asm volatile("s_waitcnt vmcnt(" #K11 ")" ::: "memory");      \
        __builtin_amdgcn_s_barrier();                                            \
        __builtin_amdgcn_sched_barrier(0);                                       \
    }

    // ---- prologue: FIFO = s0 | W0 | s1 | s2 ; retire s0, keep W0+s1+s2 ----
    stage(0, 0);
    LOADW(wc, 0);
    stage(1, 1);
    stage(2, 2);
    BARC(16, 14);

    // ---- steady phases (K=0..4): LOADW(K+1) ; stage(K+3) ; COMPUTE(K) ; BARC ----
    // end-of-phase-K keep = s(K+2) + W(K+1)... wait newest = s(K+3)+W(K+1)+s(K+2) = 16/14
    LOADW(wn, 1); stage(3, 3); COMPUTE(sX[0], wc); BARC(16, 14);   // K=0
    LOADW(wc, 2); stage(4, 4); COMPUTE(sX[1], wn); BARC(16, 14);   // K=1
    LOADW(wn, 3); stage(5, 0); COMPUTE(sX[2], wc); BARC(16, 14);   // K=2
    LOADW(wc, 4); stage(6, 1); COMPUTE(sX[3], wn); BARC(16, 14);   // K=3
    LOADW(wn, 5); stage(7, 2); COMPUTE(sX[4], wc); BARC(16, 14);   // K=4
    // K=5: no stage left; keep s7 + W6 = 12/11 (retires s6)
    LOADW(wc, 6); COMPUTE(sX[0], wn); BARC(12, 11);
    // K=6: keep W7 = 8/8 (retires s7)
    LOADW(wn, 7); COMPUTE(sX[1], wc); BARC(8, 8);
    // K=7: pure compute
    COMPUTE(sX[2], wn);
#undef BARC
#undef COMPUTE
#undef MFMA16
#undef LOADW

    float scl[4][4], shf[4][4];
    #pragma unroll
    for (int bo = 0; bo < 4; ++bo)
        #pragma unroll
        for (int r = 0; r < 4; ++r) {
            int o = o_base + wv * 64 + bo * 16 + q * 4 + r;
            float sc = gamma[o] * rsqrtf(rvar[o] + 1e-5f);
            scl[bo][r] = sc;
            shf[bo][r] = beta[o] - rmean[o] * sc;
        }
    float* outb = out + (size_t)b * COUT * HW;
    #pragma unroll
    for (int bo = 0; bo < 4; ++bo) {
        #pragma unroll
        for (int r = 0; r < 4; ++r) {
            int o = o_base + wv * 64 + bo * 16 + q * 4 + r;
            float* orow = outb + (size_t)o * HW + hw_base + m16;
            #pragma unroll
            for (int bm = 0; bm < 7; ++bm) {
                float y = acc[bo][bm][r] * scl[bo][r] + shf[bo][r];
                y = fmaxf(y, 0.f);
                __builtin_nontemporal_store(y, orow + bm * 16);
            }
        }
    }
}

// ---------------- Fallback (ws too small): round-1 single-pass ----------------
#define SW_STRIDE 72
#define SX_STRIDE 64
__global__ __launch_bounds__(256, 2)
void shiftconv_fallback(const float* __restrict__ x, const float* __restrict__ Wf,
                        const float* __restrict__ gamma, const float* __restrict__ beta,
                        const float* __restrict__ rmean, const float* __restrict__ rvar,
                        float* __restrict__ out)
{
    __shared__ unsigned short sW[NT * SW_STRIDE];
    __shared__ unsigned short sX[MT * SX_STRIDE];
    const int t = threadIdx.x;
    const int ot = blockIdx.x, mt = blockIdx.y, b = blockIdx.z;
    const int o_base = ot * NT, hw_base = mt * MT;
    const float* xb = x + (size_t)b * CIN * HW;
    const int lane = t & 63, wv = t >> 6, m16 = lane & 15, q = lane >> 4;
    f32x4 acc[2][7];
    #pragma unroll
    for (int i = 0; i < 2; ++i)
        #pragma unroll
        for (int j = 0; j < 7; ++j) acc[i][j] = (f32x4){0.f, 0.f, 0.f, 0.f};
    #pragma unroll
    for (int kk = 0; kk < CIN / BK; ++kk) {
        const int k0 = kk * BK;
        const int g = k0 >> 7;
        #pragma unroll
        for (int e0 = 0; e0 < 2; ++e0) {
            int e = t + e0 * 256;
            if (e < (BK / 4) * (MT / 4)) {
                int cq = e / 28, mq = e - cq * 28;
                int hw = hw_base + mq * 4;
                const float* src = xb + (size_t)(k0 + cq * 4) * HW;
                float4 v0, v1, v2, v3;
                if (g < 2) {
                    int shw = hw + (g == 0 ? 28 : HW - 28);
                    if (shw >= HW) shw -= HW;
                    v0 = *(const float4*)(src + 0 * HW + shw);
                    v1 = *(const float4*)(src + 1 * HW + shw);
                    v2 = *(const float4*)(src + 2 * HW + shw);
                    v3 = *(const float4*)(src + 3 * HW + shw);
                } else {
                    int h = hw / 28, w0 = hw - h * 28, base = h * 28;
                    #pragma unroll
                    for (int j = 0; j < 4; ++j) {
                        const float* row = src + j * HW + base;
                        float4 a = *(const float4*)(row + w0);
                        float4 r;
                        if (g == 2) {
                            float ex = row[(w0 + 4 < 28) ? (w0 + 4) : 0];
                            r.x = a.y; r.y = a.z; r.z = a.w; r.w = ex;
                        } else {
                            float ex = row[(w0 == 0) ? 27 : (w0 - 1)];
                            r.x = ex; r.y = a.x; r.z = a.y; r.w = a.z;
                        }
                        if (j == 0) v0 = r; else if (j == 1) v1 = r;
                        else if (j == 2) v2 = r; else v3 = r;
                    }
                }
                int m0 = mq * 4;
                { int p = (cq + 5 * (m0 + 0)) & 15;
                  *(uint2*)(&sX[(m0 + 0) * SX_STRIDE + p * 4]) = pack4(v0.x, v1.x, v2.x, v3.x); }
                { int p = (cq + 5 * (m0 + 1)) & 15;
                  *(uint2*)(&sX[(m0 + 1) * SX_STRIDE + p * 4]) = pack4(v0.y, v1.y, v2.y, v3.y); }
                { int p = (cq + 5 * (m0 + 2)) & 15;
                  *(uint2*)(&sX[(m0 + 2) * SX_STRIDE + p * 4]) = pack4(v0.z, v1.z, v2.z, v3.z); }
                { int p = (cq + 5 * (m0 + 3)) & 15;
                  *(uint2*)(&sX[(m0 + 3) * SX_STRIDE + p * 4]) = pack4(v0.w, v1.w, v2.w, v3.w); }
            }
        }
        #pragma unroll
        for (int i = 0; i < 4; ++i) {
            int e = t + i * 256;
            int ol = e >> 3, kg = (e & 7) * 8;
            const float* wr = Wf + (size_t)(o_base + ol) * CIN + k0 + kg;
            float4 a = *(const float4*)(wr);
            float4 c = *(const float4*)(wr + 4);
            uint2 lo = pack4(a.x, a.y, a.z, a.w);
            uint2 hi = pack4(c.x, c.y, c.z, c.w);
            uint4 v; v.x = lo.x; v.y = lo.y; v.z = hi.x; v.w = hi.y;
            *(uint4*)(&sW[ol * SW_STRIDE + kg]) = v;
        }
        __syncthreads();
        #pragma unroll
        for (int ks = 0; ks < BK; ks += 32) {
            short8 afrag[2];
            #pragma unroll
            for (int bo = 0; bo < 2; ++bo) {
                int row = wv * 32 + bo * 16 + m16;
                afrag[bo] = *(const short8*)(&sW[row * SW_STRIDE + ks + q * 8]);
            }
            #pragma unroll
            for (int bm = 0; bm < 7; ++bm) {
                int m = bm * 16 + m16;
                int g0 = (ks >> 2) + 2 * q;
                int p0 = (g0 + 5 * m) & 15;
                int p1 = (g0 + 1 + 5 * m) & 15;
                uint2 lo = *(const uint2*)(&sX[m * SX_STRIDE + p0 * 4]);
                uint2 hi = *(const uint2*)(&sX[m * SX_STRIDE + p1 * 4]);
                union { uint2 u2[2]; short8 s; } fb;
                fb.u2[0] = lo; fb.u2[1] = hi;
                acc[0][bm] = __builtin_amdgcn_mfma_f32_16x16x32_bf16(afrag[0], fb.s, acc[0][bm], 0, 0, 0);
                acc[1][bm] = __builtin_amdgcn_mfma_f32_16x16x32_bf16(afrag[1], fb.s, acc[1][bm], 0, 0, 0);
            }
        }
        __syncthreads();
    }
    float scl[2][4], shf[2][4];
    #pragma unroll
    for (int bo = 0; bo < 2; ++bo)
        #pragma unroll
        for (int r = 0; r < 4; ++r) {
            int o = o_base + wv * 32 + bo * 16 + q * 4 + r;
            float sc = gamma[o] * rsqrtf(rvar[o] + 1e-5f);
            scl[bo][r] = sc;
            shf[bo][r] = beta[o] - rmean[o] * sc;
        }
    float* outb = out + (size_t)b * COUT * HW;
    #pragma unroll
    for (int bo = 0; bo < 2; ++bo)
        #pragma unroll
        for (int r = 0; r < 4; ++r) {
            int o = o_base + wv * 32 + bo * 16 + q * 4 + r;
            float* orow = outb + (size_t)o * HW + hw_base + m16;
            #pragma unroll
            for (int bm = 0; bm < 7; ++bm) {
                float y = acc[bo][bm][r] * scl[bo][r] + shf[bo][r];
                y = fmaxf(y, 0.f);
                __builtin_nontemporal_store(y, orow + bm * 16);
            }
        }
}

extern "C" void kernel_launch(void* const* d_in, const int* in_sizes, int n_in,
                              void* d_out, int out_size, void* d_ws, size_t ws_size,
                              hipStream_t stream)
{
    const float* x     = (const float*)d_in[0];
    const float* W     = (const float*)d_in[1];
    const float* gamma = (const float*)d_in[2];
    const float* beta  = (const float*)d_in[3];
    const float* rmean = (const float*)d_in[4];
    const float* rvar  = (const float*)d_in[5];
    float* out = (float*)d_out;

    const size_t wb_bytes = (size_t)COUT * CIN * 2;                 // 512 KB
    const size_t xt_bytes = (size_t)BN * CIN * HW * 2;              // ~51.4 MB
    if (ws_size >= wb_bytes + xt_bytes) {
        unsigned short* Wb = (unsigned short*)d_ws;
        unsigned short* Xt = (unsigned short*)((char*)d_ws + wb_bytes);
        dim3 g1(8, 7, BN + 1);
        p1_shift_cvt<<<g1, 448, 0, stream>>>(x, W, Wb, Xt);
        p2_gemm<<<896, 256, 0, stream>>>(Wb, Xt, gamma, beta, rmean, rvar, out);
    } else {
        dim3 grid(COUT / NT, HW / MT, BN);
        shiftconv_fallback<<<grid, 256, 0, stream>>>(x, W, gamma, beta, rmean, rvar, out);
    }
}